// Round 17
// baseline (738.355 us; speedup 1.0000x reference)
//
#include <hip/hip_runtime.h>
#include <math.h>

#define HD   2048
#define NH_  16
#define DH_  128
#define SEQ_ 2048
#define B_   4
#define NT_  (B_*SEQ_)
#define EPS_ 1e-5f

typedef __attribute__((ext_vector_type(8))) __bf16 bf16x8;
typedef __attribute__((ext_vector_type(4))) __bf16 bf16x4;
typedef __attribute__((ext_vector_type(4))) float f32x4;

typedef const __attribute__((address_space(1))) void* gcptr_t;
typedef __attribute__((address_space(3))) void* lptr_t;

__device__ __forceinline__ void gload16(const void* g, void* l) {
  __builtin_amdgcn_global_load_lds((gcptr_t)g, (lptr_t)l, 16, 0, 0);
}

// ---------------- block-wide sum over 256 threads (4 waves) ----------------
__device__ __forceinline__ float block_sum256(float v, float* red) {
#pragma unroll
  for (int o = 32; o > 0; o >>= 1) v += __shfl_down(v, o);
  int lane = threadIdx.x & 63, wid = threadIdx.x >> 6;
  __syncthreads();
  if (lane == 0) red[wid] = v;
  __syncthreads();
  return red[0] + red[1] + red[2] + red[3];
}

// ---------------- workspace diagnostic (ws too small) ----------------------
__global__ void ws_diag_kernel(float* out, float v) { out[0] = v; }

// ---------------- RoPE cos/sin table (fp64 for accuracy) -------------------
__global__ void rope_table_kernel(float* __restrict__ ct, float* __restrict__ st) {
  int i = blockIdx.x * 256 + threadIdx.x;
  if (i >= SEQ_ * 64) return;
  int l = i >> 6, d = i & 63;
  double invf = exp2(-(double)d * (13.287712379549449 / 64.0));
  double ang = (double)l * invf;
  ct[i] = (float)cos(ang);
  st[i] = (float)sin(ang);
}

// ---------------- LN1 fused + bf16 round: x -> Ah --------------------------
template<bool LO>
__global__ __launch_bounds__(256) void ln1_split_kernel(const float* __restrict__ x,
    const float* __restrict__ w, const float* __restrict__ bias,
    __bf16* __restrict__ Ah, __bf16* __restrict__ Al) {
  __shared__ float red[4];
  int t = threadIdx.x;
  const float4* xr = (const float4*)(x + (size_t)blockIdx.x * HD);
  float4 a = xr[t], b = xr[t + 256];
  float s = a.x + a.y + a.z + a.w + b.x + b.y + b.z + b.w;
  s = block_sum256(s, red);
  float mu = s * (1.0f / HD);
  float dx[8] = {a.x - mu, a.y - mu, a.z - mu, a.w - mu,
                 b.x - mu, b.y - mu, b.z - mu, b.w - mu};
  float ss = 0.f;
#pragma unroll
  for (int i = 0; i < 8; ++i) ss += dx[i] * dx[i];
  ss = block_sum256(ss, red);
  float rs = rsqrtf(ss * (1.0f / HD) + EPS_);
  float4 w0 = ((const float4*)w)[t], w1 = ((const float4*)w)[t + 256];
  float4 b0 = ((const float4*)bias)[t], b1 = ((const float4*)bias)[t + 256];
  float y[8];
  y[0] = dx[0]*rs*w0.x + b0.x; y[1] = dx[1]*rs*w0.y + b0.y;
  y[2] = dx[2]*rs*w0.z + b0.z; y[3] = dx[3]*rs*w0.w + b0.w;
  y[4] = dx[4]*rs*w1.x + b1.x; y[5] = dx[5]*rs*w1.y + b1.y;
  y[6] = dx[6]*rs*w1.z + b1.z; y[7] = dx[7]*rs*w1.w + b1.w;
  bf16x4 h0, h1, l0, l1;
#pragma unroll
  for (int i = 0; i < 4; ++i) {
    h0[i] = (__bf16)y[i];     l0[i] = (__bf16)(y[i] - (float)h0[i]);
    h1[i] = (__bf16)y[i + 4]; l1[i] = (__bf16)(y[i + 4] - (float)h1[i]);
  }
  size_t base = (size_t)blockIdx.x * HD;
  *(bf16x4*)&Ah[base + 4 * t] = h0;
  *(bf16x4*)&Ah[base + 1024 + 4 * t] = h1;
  if (LO) {
    *(bf16x4*)&Al[base + 4 * t] = l0;
    *(bf16x4*)&Al[base + 1024 + 4 * t] = l1;
  }
}

// ---------------- W transpose + bf16 round: W[K][N] -> Wt[N][K] ------------
template<bool LO>
__global__ __launch_bounds__(256) void wsplit_kernel(const float* __restrict__ W,
    int K, int N, __bf16* __restrict__ Wh, __bf16* __restrict__ Wl) {
  __shared__ float ts[64][69];
  int k0 = blockIdx.x << 6, n0 = blockIdx.y << 6;
  int t = threadIdx.x;
#pragma unroll
  for (int i = 0; i < 16; ++i) {
    int lin = t + i * 256;
    int k = lin >> 6, n = lin & 63;
    ts[k][n] = W[(size_t)(k0 + k) * N + n0 + n];
  }
  __syncthreads();
#pragma unroll
  for (int i = 0; i < 16; ++i) {
    int lin = t + i * 256;
    int n = lin >> 6, k = lin & 63;
    float v = ts[k][n];
    __bf16 h = (__bf16)v;
    size_t o = (size_t)(n0 + n) * K + k0 + k;
    Wh[o] = h;
    if (LO) Wl[o] = (__bf16)(v - (float)h);
  }
}

// ---------------- fused Q/K layernorm (no bias) + RoPE, bf16 in place ------
__global__ __launch_bounds__(256) void qkln_rope_kernel(__bf16* __restrict__ qkv,
    const float* __restrict__ qw, const float* __restrict__ kw,
    const float* __restrict__ ct, const float* __restrict__ st) {
  __shared__ float red[4];
  int t = threadIdx.x;
  int tok = blockIdx.x;
  int part = blockIdx.y;
  int pos = tok & (SEQ_ - 1);
  __bf16* base = qkv + (size_t)tok * (3 * HD) + (size_t)part * HD;
  const float* w = part ? kw : qw;
  bf16x8 v8 = *(const bf16x8*)(base + 8 * t);
  float x[8];
#pragma unroll
  for (int i = 0; i < 8; ++i) x[i] = (float)v8[i];
  float s = 0.f;
#pragma unroll
  for (int i = 0; i < 8; ++i) s += x[i];
  s = block_sum256(s, red);
  float mu = s * (1.0f / HD);
  float ss = 0.f;
#pragma unroll
  for (int i = 0; i < 8; ++i) { x[i] -= mu; ss += x[i] * x[i]; }
  ss = block_sum256(ss, red);
  float rs = rsqrtf(ss * (1.0f / HD) + EPS_);
  float4 w0 = *(const float4*)&w[8 * t];
  float4 w1 = *(const float4*)&w[8 * t + 4];
  float y[8];
  y[0] = x[0]*rs*w0.x; y[1] = x[1]*rs*w0.y; y[2] = x[2]*rs*w0.z; y[3] = x[3]*rs*w0.w;
  y[4] = x[4]*rs*w1.x; y[5] = x[5]*rs*w1.y; y[6] = x[6]*rs*w1.z; y[7] = x[7]*rs*w1.w;
  float o[8];
#pragma unroll
  for (int i = 0; i < 8; ++i) o[i] = __shfl_xor(y[i], 8);
  int d = (8 * t) & 127;
  int dd = (d < 64) ? d : d - 64;
  float4 c0 = *(const float4*)&ct[pos * 64 + dd];
  float4 c1 = *(const float4*)&ct[pos * 64 + dd + 4];
  float4 s0 = *(const float4*)&st[pos * 64 + dd];
  float4 s1 = *(const float4*)&st[pos * 64 + dd + 4];
  float cv[8] = {c0.x, c0.y, c0.z, c0.w, c1.x, c1.y, c1.z, c1.w};
  float sv[8] = {s0.x, s0.y, s0.z, s0.w, s1.x, s1.y, s1.z, s1.w};
  bf16x8 o8;
  if (d < 64) {
#pragma unroll
    for (int i = 0; i < 8; ++i) o8[i] = (__bf16)(y[i] * cv[i] - o[i] * sv[i]);
  } else {
#pragma unroll
    for (int i = 0; i < 8; ++i) o8[i] = (__bf16)(y[i] * cv[i] + o[i] * sv[i]);
  }
  *(bf16x8*)(base + 8 * t) = o8;
}

// ---------------- split-bf16 MFMA GEMM (r5-proven structure) ---------------
template<int TERMS, bool OUTBF16>
__global__ __launch_bounds__(256, 2) void gemm_bf3_kernel(
    const __bf16* __restrict__ Ah, const __bf16* __restrict__ Al,
    const __bf16* __restrict__ Bh, const __bf16* __restrict__ Bl,
    const float* __restrict__ bias, void* __restrict__ C,
    int M, int N, int K) {
  __shared__ __bf16 lds[TERMS + 1][128][64];   // 32/48/64 KB
  constexpr int AL_OFF = 16384;
  constexpr int BH_OFF = (TERMS == 1) ? 16384 : 32768;
  constexpr int BL_OFF = 49152;
  const int t = threadIdx.x;
  const int lane = t & 63, wave = t >> 6;
  const int c = lane & 15, g = lane >> 4;
  const int wm = (wave & 1) << 6, wn = (wave >> 1) << 6;

  const int nwg = gridDim.x * gridDim.y;
  int lin = blockIdx.y * gridDim.x + blockIdx.x;
  int swz = (lin & 7) * (nwg >> 3) + (lin >> 3);
  const int col0 = (swz % gridDim.x) << 7;
  const int row0 = (swz / gridDim.x) << 7;

  const int srow = (wave << 5) + (lane >> 3);  // + i*8
  const int ch = lane & 7;
  size_t offA[4], offB[4];
#pragma unroll
  for (int i = 0; i < 4; ++i) {
    int rA = srow + i * 8;
    offA[i] = (size_t)(row0 + rA) * (K * 2) + (size_t)((ch ^ (rA & 7)) << 4);
    offB[i] = (size_t)(col0 + rA) * (K * 2) + (size_t)((ch ^ (rA & 7)) << 4);
  }
  const char* pAh = (const char*)Ah;
  const char* pAl = (const char*)Al;
  const char* pBh = (const char*)Bh;
  const char* pBl = (const char*)Bl;
  char* ldsb = (char*)&lds[0][0][0];

  float bias_[4];
#pragma unroll
  for (int nt = 0; nt < 4; ++nt) bias_[nt] = bias[col0 + wn + nt * 16 + c];

  f32x4 acc[4][4];
#pragma unroll
  for (int mt = 0; mt < 4; ++mt)
#pragma unroll
    for (int nt = 0; nt < 4; ++nt) acc[mt][nt] = f32x4{0.f, 0.f, 0.f, 0.f};

  for (int k0 = 0; k0 < K; k0 += 64) {
    const size_t k2 = (size_t)k0 * 2;
    __syncthreads();
#pragma unroll
    for (int i = 0; i < 4; ++i) {
      const int lr = (wave << 5) + (i << 3);
      gload16(pAh + offA[i] + k2, ldsb + (lr << 7));
      if (TERMS >= 2) gload16(pAl + offA[i] + k2, ldsb + AL_OFF + (lr << 7));
      gload16(pBh + offB[i] + k2, ldsb + BH_OFF + (lr << 7));
      if (TERMS == 3) gload16(pBl + offB[i] + k2, ldsb + BL_OFF + (lr << 7));
    }
    __syncthreads();
#pragma unroll
    for (int kc = 0; kc < 2; ++kc) {
      bf16x8 ah[4], al[4];
#pragma unroll
      for (int mt = 0; mt < 4; ++mt) {
        const int r = wm + mt * 16 + c;
        const int cb = (((kc << 2) | g) ^ (r & 7)) << 4;
        ah[mt] = *(const bf16x8*)(ldsb + (r << 7) + cb);
        if (TERMS >= 2) al[mt] = *(const bf16x8*)(ldsb + AL_OFF + (r << 7) + cb);
      }
#pragma unroll
      for (int nt = 0; nt < 4; ++nt) {
        const int r = wn + nt * 16 + c;
        const int cb = (((kc << 2) | g) ^ (r & 7)) << 4;
        bf16x8 bh = *(const bf16x8*)(ldsb + BH_OFF + (r << 7) + cb);
        bf16x8 bl;
        if (TERMS == 3) bl = *(const bf16x8*)(ldsb + BL_OFF + (r << 7) + cb);
#pragma unroll
        for (int mt = 0; mt < 4; ++mt) {
          acc[mt][nt] = __builtin_amdgcn_mfma_f32_16x16x32_bf16(ah[mt], bh, acc[mt][nt], 0, 0, 0);
          if (TERMS >= 2)
            acc[mt][nt] = __builtin_amdgcn_mfma_f32_16x16x32_bf16(al[mt], bh, acc[mt][nt], 0, 0, 0);
          if (TERMS == 3)
            acc[mt][nt] = __builtin_amdgcn_mfma_f32_16x16x32_bf16(ah[mt], bl, acc[mt][nt], 0, 0, 0);
        }
      }
    }
  }

#pragma unroll
  for (int mt = 0; mt < 4; ++mt) {
#pragma unroll
    for (int r = 0; r < 4; ++r) {
      const size_t row = (size_t)(row0 + wm + mt * 16 + g * 4 + r);
#pragma unroll
      for (int nt = 0; nt < 4; ++nt) {
        float v = acc[mt][nt][r] + bias_[nt];
        size_t idx = row * N + col0 + wn + nt * 16 + c;
        if (OUTBF16) ((__bf16*)C)[idx] = (__bf16)v;
        else         ((float*)C)[idx] = v;
      }
    }
  }
}

// ---------------- flash attention, bf16 MFMA, 128 q-rows per block ---------
// r17: latency-bound fixes.
//  * Pl ALIASES Kb (K tile dead after QK^T): LDS 48->32KB, more blocks/CU.
//    Needs barrier between QK-reads and P-writes (after the mxv shuffles).
//  * V staging vectorized: thread = (keyblock t&7, dimquad t>>3); 8 x b64
//    global loads (64B/key segments) + in-reg 8x4 transpose + 4 x b128
//    swizzled LDS writes. Replaces 32 scalar ds_write_b16. Read side
//    unchanged (proven layout: row=dim, chunk kb stored at kb^(row&7)).
//  * Prefetch removed (r14 proved neutral; frees VGPR).
//  * exp2f with folded SC*log2e (saves one mul per exp).
__global__ __launch_bounds__(256, 2) void attn_mfma_kernel(
    const __bf16* __restrict__ qkv, __bf16* __restrict__ Oh) {
  __shared__ __bf16 KbPl[64 * 128];   // K during QK; P during PV (aliased)
  __shared__ __bf16 Vt[128 * 64];     // V^T [dim][key], XOR-swizzled
  const int bh = blockIdx.y, b = bh >> 4, h = bh & 15;
  const int q0 = blockIdx.x << 7;
  const int t = threadIdx.x;
  const int lane = t & 63, wave = t >> 6, g = lane >> 4, c = lane & 15;
  const int wq = wave * 32;
  const size_t rstr = 3 * HD;
  const __bf16* Qg = qkv + (size_t)b * SEQ_ * rstr + (size_t)h * DH_;
  const __bf16* Kg = Qg + HD;
  const __bf16* Vg = Qg + 2 * HD;
  const float SCL2 = 0.12754374742764546f;  // (1/sqrt(128)) * log2(e)
  const float THR  = 90.51f;                // 8 * sqrt(128)

  bf16x8 qf[2][4];
#pragma unroll
  for (int rt = 0; rt < 2; ++rt) {
    const __bf16* qr = Qg + (size_t)(q0 + wq + rt * 16 + c) * rstr;
#pragma unroll
    for (int kc = 0; kc < 4; ++kc)
      qf[rt][kc] = *(const bf16x8*)(qr + kc * 32 + g * 8);
  }

  f32x4 Oa[2][8];
#pragma unroll
  for (int rt = 0; rt < 2; ++rt)
#pragma unroll
    for (int dt = 0; dt < 8; ++dt) Oa[rt][dt] = f32x4{0.f, 0.f, 0.f, 0.f};
  float m_[2][4], l_[2][4];
#pragma unroll
  for (int rt = 0; rt < 2; ++rt)
#pragma unroll
    for (int r = 0; r < 4; ++r) { m_[rt][r] = -1e30f; l_[rt][r] = 0.f; }

  const int krow  = t >> 4;                // K stage: row 0..15 (+16i)
  const int kch   = t & 15;
  const int kswc  = kch ^ (krow & 7);
  const int vkb   = t & 7;                 // V stage: key block (8 keys)
  const int vdimq = t >> 3;                // dims vdimq*4 .. +3
  const int c7    = c & 7;

  for (int kt = 0; kt < SEQ_; kt += 64) {
    // ---- global loads (issued before barrier; covered by barrier wait) ----
    bf16x8 kv[4];
#pragma unroll
    for (int i = 0; i < 4; ++i)
      kv[i] = *(const bf16x8*)(Kg + (size_t)(kt + krow + i * 16) * rstr + kch * 8);
    bf16x4 vv4[8];
#pragma unroll
    for (int j = 0; j < 8; ++j)
      vv4[j] = *(const bf16x4*)(Vg + (size_t)(kt + vkb * 8 + j) * rstr + vdimq * 4);
    __syncthreads();   // barrier1: all waves' prev PV (Pl+Vt) reads done
    // ---- stage K (vector, swizzled) ----
#pragma unroll
    for (int i = 0; i < 4; ++i)
      *(bf16x8*)&KbPl[(krow + i * 16) * 128 + kswc * 8] = kv[i];
    // ---- stage V^T (in-reg 8x4 transpose, 4 x b128 swizzled writes) ----
#pragma unroll
    for (int dd = 0; dd < 4; ++dd) {
      bf16x8 wr;
#pragma unroll
      for (int j = 0; j < 8; ++j) wr[j] = vv4[j][dd];
      const int row = vdimq * 4 + dd;
      *(bf16x8*)&Vt[row * 64 + ((vkb ^ (row & 7)) << 3)] = wr;
    }
    __syncthreads();   // barrier2: staged data visible
    // ---- S = Q K^T ----
    f32x4 Sa[2][4];
#pragma unroll
    for (int rt = 0; rt < 2; ++rt)
#pragma unroll
      for (int nt = 0; nt < 4; ++nt) Sa[rt][nt] = f32x4{0.f, 0.f, 0.f, 0.f};
#pragma unroll
    for (int nt = 0; nt < 4; ++nt) {
      bf16x8 kf[4];
#pragma unroll
      for (int kc = 0; kc < 4; ++kc)
        kf[kc] = *(bf16x8*)&KbPl[(nt * 16 + c) * 128 + (((kc * 4 + g) ^ c7) << 3)];
#pragma unroll
      for (int kc = 0; kc < 4; ++kc) {
        Sa[0][nt] = __builtin_amdgcn_mfma_f32_16x16x32_bf16(qf[0][kc], kf[kc], Sa[0][nt], 0, 0, 0);
        Sa[1][nt] = __builtin_amdgcn_mfma_f32_16x16x32_bf16(qf[1][kc], kf[kc], Sa[1][nt], 0, 0, 0);
      }
    }
    // ---- row maxes (register/shfl only) ----
    float mxv[2][4];
#pragma unroll
    for (int rt = 0; rt < 2; ++rt) {
#pragma unroll
      for (int r = 0; r < 4; ++r) {
        float mx = fmaxf(fmaxf(Sa[rt][0][r], Sa[rt][1][r]),
                         fmaxf(Sa[rt][2][r], Sa[rt][3][r]));
#pragma unroll
        for (int off = 1; off < 16; off <<= 1) mx = fmaxf(mx, __shfl_xor(mx, off));
        mxv[rt][r] = mx;
      }
    }
    __syncthreads();   // barrier3: all waves done reading KbPl as K
    // ---- defer-max ----
    bool big = false;
#pragma unroll
    for (int rt = 0; rt < 2; ++rt)
#pragma unroll
      for (int r = 0; r < 4; ++r) big = big || (mxv[rt][r] > m_[rt][r] + THR);
    if (__any(big)) {
      float fs_[2][4];
#pragma unroll
      for (int rt = 0; rt < 2; ++rt) {
#pragma unroll
        for (int r = 0; r < 4; ++r) {
          float mn = fmaxf(m_[rt][r], mxv[rt][r]);
          float fs = exp2f((m_[rt][r] - mn) * SCL2);
          m_[rt][r] = mn;
          l_[rt][r] *= fs;
          fs_[rt][r] = fs;
        }
      }
#pragma unroll
      for (int rt = 0; rt < 2; ++rt)
#pragma unroll
        for (int dt = 0; dt < 8; ++dt)
#pragma unroll
          for (int r = 0; r < 4; ++r) Oa[rt][dt][r] *= fs_[rt][r];
    }
    // ---- P = exp2(SCL2*(S-m)) -> Pl (aliased over Kb; own-wave rows) ----
#pragma unroll
    for (int rt = 0; rt < 2; ++rt) {
#pragma unroll
      for (int r = 0; r < 4; ++r) {
        const float mn = m_[rt][r];
        const int prow = wq + rt * 16 + 4 * g + r;
        const int psw = prow & 7;
        float ps = 0.f;
#pragma unroll
        for (int nt = 0; nt < 4; ++nt) {
          float p = exp2f((Sa[rt][nt][r] - mn) * SCL2);
          KbPl[prow * 64 + (((nt * 2 + (c >> 3)) ^ psw) << 3) + (c & 7)] = (__bf16)p;
          ps += p;
        }
#pragma unroll
        for (int off = 1; off < 16; off <<= 1) ps += __shfl_xor(ps, off);
        l_[rt][r] += ps;
      }
    }
    // ---- O += P V (Pl rows own-wave; Vt stable until next barrier1) ----
#pragma unroll
    for (int k2 = 0; k2 < 2; ++k2) {
      const int pch = ((k2 * 4 + g) ^ c7) << 3;
      bf16x8 pf0 = *(bf16x8*)&KbPl[(wq + c) * 64 + pch];
      bf16x8 pf1 = *(bf16x8*)&KbPl[(wq + 16 + c) * 64 + pch];
#pragma unroll
      for (int dt = 0; dt < 8; ++dt) {
        bf16x8 vf = *(bf16x8*)&Vt[(dt * 16 + c) * 64 + pch];
        Oa[0][dt] = __builtin_amdgcn_mfma_f32_16x16x32_bf16(pf0, vf, Oa[0][dt], 0, 0, 0);
        Oa[1][dt] = __builtin_amdgcn_mfma_f32_16x16x32_bf16(pf1, vf, Oa[1][dt], 0, 0, 0);
      }
    }
  }
#pragma unroll
  for (int rt = 0; rt < 2; ++rt) {
#pragma unroll
    for (int r = 0; r < 4; ++r) {
      float inv = 1.0f / l_[rt][r];
      size_t obase = (size_t)(b * SEQ_ + q0 + wq + rt * 16 + 4 * g + r) * HD + h * DH_;
#pragma unroll
      for (int dt = 0; dt < 8; ++dt)
        Oh[obase + dt * 16 + c] = (__bf16)(Oa[rt][dt][r] * inv);
    }
  }
}

// ---------------------------------------------------------------------------
extern "C" void kernel_launch(void* const* d_in, const int* in_sizes, int n_in,
                              void* d_out, int out_size, void* d_ws, size_t ws_size,
                              hipStream_t stream) {
  const float* x    = (const float*)d_in[0];
  const float* ln1w = (const float*)d_in[1];
  const float* ln1b = (const float*)d_in[2];
  const float* Wqkv = (const float*)d_in[3];
  const float* bqkv = (const float*)d_in[4];
  const float* qlnw = (const float*)d_in[5];
  const float* klnw = (const float*)d_in[6];
  const float* Wo   = (const float*)d_in[7];
  const float* bo   = (const float*)d_in[8];
  float* out = (float*)d_out;

  // ws layout (bytes): qkv bf16 | Ah | Al | Wth | Wtl | ctab | stab  (~209 MiB)
  const size_t qkv_b = (size_t)NT_ * 3 * HD * 2;
  const size_t a_b   = (size_t)NT_ * HD * 2;
  const size_t w_b   = (size_t)3 * HD * HD * 2;
  const size_t t_b   = (size_t)SEQ_ * 64 * 4;
  const size_t need  = qkv_b + 2 * a_b + 2 * w_b + 2 * t_b;
  if (ws_size < need) {
    ws_diag_kernel<<<1, 1, 0, stream>>>(out, (float)(ws_size >> 20));
    return;
  }
  char* w = (char*)d_ws;
  __bf16* qkvb = (__bf16*)w;              w += qkv_b;
  __bf16* Ah   = (__bf16*)w;              w += a_b;
  __bf16* Al   = (__bf16*)w;              w += a_b;
  __bf16* Wth  = (__bf16*)w;              w += w_b;
  __bf16* Wtl  = (__bf16*)w;              w += w_b;
  float*  ctab = (float*)w;               w += t_b;
  float*  stab = (float*)w;

  rope_table_kernel<<<(SEQ_ * 64 + 255) / 256, 256, 0, stream>>>(ctab, stab);
  ln1_split_kernel<false><<<NT_, 256, 0, stream>>>(x, ln1w, ln1b, Ah, Al);
  wsplit_kernel<false><<<dim3(HD / 64, 3 * HD / 64), 256, 0, stream>>>(
      Wqkv, HD, 3 * HD, Wth, Wtl);               // hi only (1-term QKV)
  gemm_bf3_kernel<1, true><<<dim3(3 * HD / 128, NT_ / 128), 256, 0, stream>>>(
      Ah, nullptr, Wth, nullptr, bqkv, qkvb, NT_, 3 * HD, HD);
  qkln_rope_kernel<<<dim3(NT_, 2), 256, 0, stream>>>(
      qkvb, qlnw, klnw, ctab, stab);
  wsplit_kernel<false><<<dim3(HD / 64, HD / 64), 256, 0, stream>>>(
      Wo, HD, HD, Wth, Wtl);                     // hi only (1-term Wo)
  attn_mfma_kernel<<<dim3(SEQ_ / 128, B_ * NH_), 256, 0, stream>>>(
      qkvb, Ah);                                 // O -> Ah (single bf16)
  gemm_bf3_kernel<1, false><<<dim3(HD / 128, NT_ / 128), 256, 0, stream>>>(
      Ah, nullptr, Wth, nullptr, bo, out, NT_, HD, HD);
}

// Round 18
// 708.834 us; speedup vs baseline: 1.0416x; 1.0416x over previous
//
#include <hip/hip_runtime.h>
#include <math.h>

#define HD   2048
#define NH_  16
#define DH_  128
#define SEQ_ 2048
#define B_   4
#define NT_  (B_*SEQ_)
#define EPS_ 1e-5f

typedef __attribute__((ext_vector_type(8))) __bf16 bf16x8;
typedef __attribute__((ext_vector_type(4))) __bf16 bf16x4;
typedef __attribute__((ext_vector_type(4))) float f32x4;

typedef const __attribute__((address_space(1))) void* gcptr_t;
typedef __attribute__((address_space(3))) void* lptr_t;

__device__ __forceinline__ void gload16(const void* g, void* l) {
  __builtin_amdgcn_global_load_lds((gcptr_t)g, (lptr_t)l, 16, 0, 0);
}

// ---------------- block-wide sum over 256 threads (4 waves) ----------------
__device__ __forceinline__ float block_sum256(float v, float* red) {
#pragma unroll
  for (int o = 32; o > 0; o >>= 1) v += __shfl_down(v, o);
  int lane = threadIdx.x & 63, wid = threadIdx.x >> 6;
  __syncthreads();
  if (lane == 0) red[wid] = v;
  __syncthreads();
  return red[0] + red[1] + red[2] + red[3];
}

// ---------------- workspace diagnostic (ws too small) ----------------------
__global__ void ws_diag_kernel(float* out, float v) { out[0] = v; }

// ---------------- RoPE cos/sin table (fp64 for accuracy) -------------------
__global__ void rope_table_kernel(float* __restrict__ ct, float* __restrict__ st) {
  int i = blockIdx.x * 256 + threadIdx.x;
  if (i >= SEQ_ * 64) return;
  int l = i >> 6, d = i & 63;
  double invf = exp2(-(double)d * (13.287712379549449 / 64.0));
  double ang = (double)l * invf;
  ct[i] = (float)cos(ang);
  st[i] = (float)sin(ang);
}

// ---------------- LN1 fused + bf16 round: x -> Ah --------------------------
template<bool LO>
__global__ __launch_bounds__(256) void ln1_split_kernel(const float* __restrict__ x,
    const float* __restrict__ w, const float* __restrict__ bias,
    __bf16* __restrict__ Ah, __bf16* __restrict__ Al) {
  __shared__ float red[4];
  int t = threadIdx.x;
  const float4* xr = (const float4*)(x + (size_t)blockIdx.x * HD);
  float4 a = xr[t], b = xr[t + 256];
  float s = a.x + a.y + a.z + a.w + b.x + b.y + b.z + b.w;
  s = block_sum256(s, red);
  float mu = s * (1.0f / HD);
  float dx[8] = {a.x - mu, a.y - mu, a.z - mu, a.w - mu,
                 b.x - mu, b.y - mu, b.z - mu, b.w - mu};
  float ss = 0.f;
#pragma unroll
  for (int i = 0; i < 8; ++i) ss += dx[i] * dx[i];
  ss = block_sum256(ss, red);
  float rs = rsqrtf(ss * (1.0f / HD) + EPS_);
  float4 w0 = ((const float4*)w)[t], w1 = ((const float4*)w)[t + 256];
  float4 b0 = ((const float4*)bias)[t], b1 = ((const float4*)bias)[t + 256];
  float y[8];
  y[0] = dx[0]*rs*w0.x + b0.x; y[1] = dx[1]*rs*w0.y + b0.y;
  y[2] = dx[2]*rs*w0.z + b0.z; y[3] = dx[3]*rs*w0.w + b0.w;
  y[4] = dx[4]*rs*w1.x + b1.x; y[5] = dx[5]*rs*w1.y + b1.y;
  y[6] = dx[6]*rs*w1.z + b1.z; y[7] = dx[7]*rs*w1.w + b1.w;
  bf16x4 h0, h1, l0, l1;
#pragma unroll
  for (int i = 0; i < 4; ++i) {
    h0[i] = (__bf16)y[i];     l0[i] = (__bf16)(y[i] - (float)h0[i]);
    h1[i] = (__bf16)y[i + 4]; l1[i] = (__bf16)(y[i + 4] - (float)h1[i]);
  }
  size_t base = (size_t)blockIdx.x * HD;
  *(bf16x4*)&Ah[base + 4 * t] = h0;
  *(bf16x4*)&Ah[base + 1024 + 4 * t] = h1;
  if (LO) {
    *(bf16x4*)&Al[base + 4 * t] = l0;
    *(bf16x4*)&Al[base + 1024 + 4 * t] = l1;
  }
}

// ---------------- W transpose + bf16 round: W[K][N] -> Wt[N][K] ------------
template<bool LO>
__global__ __launch_bounds__(256) void wsplit_kernel(const float* __restrict__ W,
    int K, int N, __bf16* __restrict__ Wh, __bf16* __restrict__ Wl) {
  __shared__ float ts[64][69];
  int k0 = blockIdx.x << 6, n0 = blockIdx.y << 6;
  int t = threadIdx.x;
#pragma unroll
  for (int i = 0; i < 16; ++i) {
    int lin = t + i * 256;
    int k = lin >> 6, n = lin & 63;
    ts[k][n] = W[(size_t)(k0 + k) * N + n0 + n];
  }
  __syncthreads();
#pragma unroll
  for (int i = 0; i < 16; ++i) {
    int lin = t + i * 256;
    int n = lin >> 6, k = lin & 63;
    float v = ts[k][n];
    __bf16 h = (__bf16)v;
    size_t o = (size_t)(n0 + n) * K + k0 + k;
    Wh[o] = h;
    if (LO) Wl[o] = (__bf16)(v - (float)h);
  }
}

// ---------------- fused Q/K layernorm (no bias) + RoPE, bf16 in place ------
__global__ __launch_bounds__(256) void qkln_rope_kernel(__bf16* __restrict__ qkv,
    const float* __restrict__ qw, const float* __restrict__ kw,
    const float* __restrict__ ct, const float* __restrict__ st) {
  __shared__ float red[4];
  int t = threadIdx.x;
  int tok = blockIdx.x;
  int part = blockIdx.y;
  int pos = tok & (SEQ_ - 1);
  __bf16* base = qkv + (size_t)tok * (3 * HD) + (size_t)part * HD;
  const float* w = part ? kw : qw;
  bf16x8 v8 = *(const bf16x8*)(base + 8 * t);
  float x[8];
#pragma unroll
  for (int i = 0; i < 8; ++i) x[i] = (float)v8[i];
  float s = 0.f;
#pragma unroll
  for (int i = 0; i < 8; ++i) s += x[i];
  s = block_sum256(s, red);
  float mu = s * (1.0f / HD);
  float ss = 0.f;
#pragma unroll
  for (int i = 0; i < 8; ++i) { x[i] -= mu; ss += x[i] * x[i]; }
  ss = block_sum256(ss, red);
  float rs = rsqrtf(ss * (1.0f / HD) + EPS_);
  float4 w0 = *(const float4*)&w[8 * t];
  float4 w1 = *(const float4*)&w[8 * t + 4];
  float y[8];
  y[0] = x[0]*rs*w0.x; y[1] = x[1]*rs*w0.y; y[2] = x[2]*rs*w0.z; y[3] = x[3]*rs*w0.w;
  y[4] = x[4]*rs*w1.x; y[5] = x[5]*rs*w1.y; y[6] = x[6]*rs*w1.z; y[7] = x[7]*rs*w1.w;
  float o[8];
#pragma unroll
  for (int i = 0; i < 8; ++i) o[i] = __shfl_xor(y[i], 8);
  int d = (8 * t) & 127;
  int dd = (d < 64) ? d : d - 64;
  float4 c0 = *(const float4*)&ct[pos * 64 + dd];
  float4 c1 = *(const float4*)&ct[pos * 64 + dd + 4];
  float4 s0 = *(const float4*)&st[pos * 64 + dd];
  float4 s1 = *(const float4*)&st[pos * 64 + dd + 4];
  float cv[8] = {c0.x, c0.y, c0.z, c0.w, c1.x, c1.y, c1.z, c1.w};
  float sv[8] = {s0.x, s0.y, s0.z, s0.w, s1.x, s1.y, s1.z, s1.w};
  bf16x8 o8;
  if (d < 64) {
#pragma unroll
    for (int i = 0; i < 8; ++i) o8[i] = (__bf16)(y[i] * cv[i] - o[i] * sv[i]);
  } else {
#pragma unroll
    for (int i = 0; i < 8; ++i) o8[i] = (__bf16)(y[i] * cv[i] + o[i] * sv[i]);
  }
  *(bf16x8*)(base + 8 * t) = o8;
}

// ---------------- split-bf16 MFMA GEMM (r5-proven structure) ---------------
template<int TERMS, bool OUTBF16>
__global__ __launch_bounds__(256, 2) void gemm_bf3_kernel(
    const __bf16* __restrict__ Ah, const __bf16* __restrict__ Al,
    const __bf16* __restrict__ Bh, const __bf16* __restrict__ Bl,
    const float* __restrict__ bias, void* __restrict__ C,
    int M, int N, int K) {
  __shared__ __bf16 lds[TERMS + 1][128][64];   // 32/48/64 KB
  constexpr int AL_OFF = 16384;
  constexpr int BH_OFF = (TERMS == 1) ? 16384 : 32768;
  constexpr int BL_OFF = 49152;
  const int t = threadIdx.x;
  const int lane = t & 63, wave = t >> 6;
  const int c = lane & 15, g = lane >> 4;
  const int wm = (wave & 1) << 6, wn = (wave >> 1) << 6;

  const int nwg = gridDim.x * gridDim.y;
  int lin = blockIdx.y * gridDim.x + blockIdx.x;
  int swz = (lin & 7) * (nwg >> 3) + (lin >> 3);
  const int col0 = (swz % gridDim.x) << 7;
  const int row0 = (swz / gridDim.x) << 7;

  const int srow = (wave << 5) + (lane >> 3);  // + i*8
  const int ch = lane & 7;
  size_t offA[4], offB[4];
#pragma unroll
  for (int i = 0; i < 4; ++i) {
    int rA = srow + i * 8;
    offA[i] = (size_t)(row0 + rA) * (K * 2) + (size_t)((ch ^ (rA & 7)) << 4);
    offB[i] = (size_t)(col0 + rA) * (K * 2) + (size_t)((ch ^ (rA & 7)) << 4);
  }
  const char* pAh = (const char*)Ah;
  const char* pAl = (const char*)Al;
  const char* pBh = (const char*)Bh;
  const char* pBl = (const char*)Bl;
  char* ldsb = (char*)&lds[0][0][0];

  float bias_[4];
#pragma unroll
  for (int nt = 0; nt < 4; ++nt) bias_[nt] = bias[col0 + wn + nt * 16 + c];

  f32x4 acc[4][4];
#pragma unroll
  for (int mt = 0; mt < 4; ++mt)
#pragma unroll
    for (int nt = 0; nt < 4; ++nt) acc[mt][nt] = f32x4{0.f, 0.f, 0.f, 0.f};

  for (int k0 = 0; k0 < K; k0 += 64) {
    const size_t k2 = (size_t)k0 * 2;
    __syncthreads();
#pragma unroll
    for (int i = 0; i < 4; ++i) {
      const int lr = (wave << 5) + (i << 3);
      gload16(pAh + offA[i] + k2, ldsb + (lr << 7));
      if (TERMS >= 2) gload16(pAl + offA[i] + k2, ldsb + AL_OFF + (lr << 7));
      gload16(pBh + offB[i] + k2, ldsb + BH_OFF + (lr << 7));
      if (TERMS == 3) gload16(pBl + offB[i] + k2, ldsb + BL_OFF + (lr << 7));
    }
    __syncthreads();
#pragma unroll
    for (int kc = 0; kc < 2; ++kc) {
      bf16x8 ah[4], al[4];
#pragma unroll
      for (int mt = 0; mt < 4; ++mt) {
        const int r = wm + mt * 16 + c;
        const int cb = (((kc << 2) | g) ^ (r & 7)) << 4;
        ah[mt] = *(const bf16x8*)(ldsb + (r << 7) + cb);
        if (TERMS >= 2) al[mt] = *(const bf16x8*)(ldsb + AL_OFF + (r << 7) + cb);
      }
#pragma unroll
      for (int nt = 0; nt < 4; ++nt) {
        const int r = wn + nt * 16 + c;
        const int cb = (((kc << 2) | g) ^ (r & 7)) << 4;
        bf16x8 bh = *(const bf16x8*)(ldsb + BH_OFF + (r << 7) + cb);
        bf16x8 bl;
        if (TERMS == 3) bl = *(const bf16x8*)(ldsb + BL_OFF + (r << 7) + cb);
#pragma unroll
        for (int mt = 0; mt < 4; ++mt) {
          acc[mt][nt] = __builtin_amdgcn_mfma_f32_16x16x32_bf16(ah[mt], bh, acc[mt][nt], 0, 0, 0);
          if (TERMS >= 2)
            acc[mt][nt] = __builtin_amdgcn_mfma_f32_16x16x32_bf16(al[mt], bh, acc[mt][nt], 0, 0, 0);
          if (TERMS == 3)
            acc[mt][nt] = __builtin_amdgcn_mfma_f32_16x16x32_bf16(ah[mt], bl, acc[mt][nt], 0, 0, 0);
        }
      }
    }
  }

#pragma unroll
  for (int mt = 0; mt < 4; ++mt) {
#pragma unroll
    for (int r = 0; r < 4; ++r) {
      const size_t row = (size_t)(row0 + wm + mt * 16 + g * 4 + r);
#pragma unroll
      for (int nt = 0; nt < 4; ++nt) {
        float v = acc[mt][nt][r] + bias_[nt];
        size_t idx = row * N + col0 + wn + nt * 16 + c;
        if (OUTBF16) ((__bf16*)C)[idx] = (__bf16)v;
        else         ((float*)C)[idx] = v;
      }
    }
  }
}

// ---------------- flash attention, bf16 MFMA, 128 q-rows per block ---------
// r18 = r16 attn (322us proven: 16B V loads, prefetch, __expf) + EXACTLY ONE
// change: Pl aliases Kb (K dead after QK^T) -> LDS 48->32KB -> 4 blocks/CU,
// grid 1024 = 4 x 256 CU quantizes perfectly. One extra barrier placed after
// the register-only defer-max block (shuffle/VALU work overlaps the sync).
__global__ __launch_bounds__(256, 2) void attn_mfma_kernel(
    const __bf16* __restrict__ qkv, __bf16* __restrict__ Oh) {
  __shared__ __bf16 KbPl[64 * 128];   // K during QK^T; P during PV (aliased)
  __shared__ __bf16 Vt[128 * 64];
  const int bh = blockIdx.y, b = bh >> 4, h = bh & 15;
  const int q0 = blockIdx.x << 7;
  const int t = threadIdx.x;
  const int lane = t & 63, wave = t >> 6, g = lane >> 4, c = lane & 15;
  const int wq = wave * 32;
  const size_t rstr = 3 * HD;
  const __bf16* Qg = qkv + (size_t)b * SEQ_ * rstr + (size_t)h * DH_;
  const __bf16* Kg = Qg + HD;
  const __bf16* Vg = Qg + 2 * HD;
  const float SC  = 0.08838834764831845f;  // 1/sqrt(128)
  const float THR = 90.51f;                // 8 / SC

  bf16x8 qf[2][4];
#pragma unroll
  for (int rt = 0; rt < 2; ++rt) {
    const __bf16* qr = Qg + (size_t)(q0 + wq + rt * 16 + c) * rstr;
#pragma unroll
    for (int kc = 0; kc < 4; ++kc)
      qf[rt][kc] = *(const bf16x8*)(qr + kc * 32 + g * 8);
  }

  f32x4 Oa[2][8];
#pragma unroll
  for (int rt = 0; rt < 2; ++rt)
#pragma unroll
    for (int dt = 0; dt < 8; ++dt) Oa[rt][dt] = f32x4{0.f, 0.f, 0.f, 0.f};
  float m_[2][4], l_[2][4];
#pragma unroll
  for (int rt = 0; rt < 2; ++rt)
#pragma unroll
    for (int r = 0; r < 4; ++r) { m_[rt][r] = -1e30f; l_[rt][r] = 0.f; }

  const int krow = t >> 4;
  const int kch  = t & 15;
  const int kswc = kch ^ (krow & 7);
  const int vkey = t & 63;
  const int vd0  = (t >> 6) * 32;
  const int c7   = c & 7;

  bf16x8 kv[4], vv[4];
#define LOADT(KT)                                                            \
  {                                                                          \
    _Pragma("unroll")                                                        \
    for (int i = 0; i < 4; ++i)                                              \
      kv[i] = *(const bf16x8*)(Kg + (size_t)((KT) + krow + i * 16) * rstr + kch * 8); \
    _Pragma("unroll")                                                        \
    for (int i = 0; i < 4; ++i)                                              \
      vv[i] = *(const bf16x8*)(Vg + (size_t)((KT) + vkey) * rstr + vd0 + i * 8); \
  }
  LOADT(0);

  for (int kt = 0; kt < SEQ_; kt += 64) {
    __syncthreads();   // barrier1: all waves' prev-tile PV reads done
#pragma unroll
    for (int i = 0; i < 4; ++i) {
      *(bf16x8*)&KbPl[(krow + i * 16) * 128 + kswc * 8] = kv[i];
#pragma unroll
      for (int j = 0; j < 8; ++j)
        Vt[(vd0 + i * 8 + j) * 64 + (((vkey >> 3) ^ j) << 3) + (vkey & 7)] = vv[i][j];
    }
    __syncthreads();   // barrier2: staged data visible
    if (kt + 64 < SEQ_) LOADT(kt + 64);
    // ---- S = Q K^T (reads KbPl as K) ----
    f32x4 Sa[2][4];
#pragma unroll
    for (int rt = 0; rt < 2; ++rt)
#pragma unroll
      for (int nt = 0; nt < 4; ++nt) Sa[rt][nt] = f32x4{0.f, 0.f, 0.f, 0.f};
#pragma unroll
    for (int nt = 0; nt < 4; ++nt) {
      bf16x8 kf[4];
#pragma unroll
      for (int kc = 0; kc < 4; ++kc)
        kf[kc] = *(bf16x8*)&KbPl[(nt * 16 + c) * 128 + (((kc * 4 + g) ^ c7) << 3)];
#pragma unroll
      for (int kc = 0; kc < 4; ++kc) {
        Sa[0][nt] = __builtin_amdgcn_mfma_f32_16x16x32_bf16(qf[0][kc], kf[kc], Sa[0][nt], 0, 0, 0);
        Sa[1][nt] = __builtin_amdgcn_mfma_f32_16x16x32_bf16(qf[1][kc], kf[kc], Sa[1][nt], 0, 0, 0);
      }
    }
    // ---- row maxes (register/shfl only) ----
    float mxv[2][4];
#pragma unroll
    for (int rt = 0; rt < 2; ++rt) {
#pragma unroll
      for (int r = 0; r < 4; ++r) {
        float mx = fmaxf(fmaxf(Sa[rt][0][r], Sa[rt][1][r]),
                         fmaxf(Sa[rt][2][r], Sa[rt][3][r]));
#pragma unroll
        for (int off = 1; off < 16; off <<= 1) mx = fmaxf(mx, __shfl_xor(mx, off));
        mxv[rt][r] = mx;
      }
    }
    // ---- defer-max (register only) ----
    bool big = false;
#pragma unroll
    for (int rt = 0; rt < 2; ++rt)
#pragma unroll
      for (int r = 0; r < 4; ++r) big = big || (mxv[rt][r] > m_[rt][r] + THR);
    if (__any(big)) {
      float fs_[2][4];
#pragma unroll
      for (int rt = 0; rt < 2; ++rt) {
#pragma unroll
        for (int r = 0; r < 4; ++r) {
          float mn = fmaxf(m_[rt][r], mxv[rt][r]);
          float fs = __expf((m_[rt][r] - mn) * SC);
          m_[rt][r] = mn;
          l_[rt][r] *= fs;
          fs_[rt][r] = fs;
        }
      }
#pragma unroll
      for (int rt = 0; rt < 2; ++rt)
#pragma unroll
        for (int dt = 0; dt < 8; ++dt)
#pragma unroll
          for (int r = 0; r < 4; ++r) Oa[rt][dt][r] *= fs_[rt][r];
    }
    __syncthreads();   // barrier3: all waves' K reads done -> safe to write P
    // ---- P = exp(SC*(S-m)) -> KbPl (as P, 64-wide rows; own-wave rows) ----
#pragma unroll
    for (int rt = 0; rt < 2; ++rt) {
#pragma unroll
      for (int r = 0; r < 4; ++r) {
        const float mn = m_[rt][r];
        const int prow = wq + rt * 16 + 4 * g + r;
        const int psw = prow & 7;
        float ps = 0.f;
#pragma unroll
        for (int nt = 0; nt < 4; ++nt) {
          float p = __expf((Sa[rt][nt][r] - mn) * SC);
          KbPl[prow * 64 + (((nt * 2 + (c >> 3)) ^ psw) << 3) + (c & 7)] = (__bf16)p;
          ps += p;
        }
#pragma unroll
        for (int off = 1; off < 16; off <<= 1) ps += __shfl_xor(ps, off);
        l_[rt][r] += ps;
      }
    }
    // ---- O += P V (P rows own-wave; Vt stable until next barrier1) ----
#pragma unroll
    for (int k2 = 0; k2 < 2; ++k2) {
      const int pch = ((k2 * 4 + g) ^ c7) << 3;
      bf16x8 pf0 = *(bf16x8*)&KbPl[(wq + c) * 64 + pch];
      bf16x8 pf1 = *(bf16x8*)&KbPl[(wq + 16 + c) * 64 + pch];
#pragma unroll
      for (int dt = 0; dt < 8; ++dt) {
        bf16x8 vf = *(bf16x8*)&Vt[(dt * 16 + c) * 64 + pch];
        Oa[0][dt] = __builtin_amdgcn_mfma_f32_16x16x32_bf16(pf0, vf, Oa[0][dt], 0, 0, 0);
        Oa[1][dt] = __builtin_amdgcn_mfma_f32_16x16x32_bf16(pf1, vf, Oa[1][dt], 0, 0, 0);
      }
    }
  }
#undef LOADT
#pragma unroll
  for (int rt = 0; rt < 2; ++rt) {
#pragma unroll
    for (int r = 0; r < 4; ++r) {
      float inv = 1.0f / l_[rt][r];
      size_t obase = (size_t)(b * SEQ_ + q0 + wq + rt * 16 + 4 * g + r) * HD + h * DH_;
#pragma unroll
      for (int dt = 0; dt < 8; ++dt)
        Oh[obase + dt * 16 + c] = (__bf16)(Oa[rt][dt][r] * inv);
    }
  }
}

// ---------------------------------------------------------------------------
extern "C" void kernel_launch(void* const* d_in, const int* in_sizes, int n_in,
                              void* d_out, int out_size, void* d_ws, size_t ws_size,
                              hipStream_t stream) {
  const float* x    = (const float*)d_in[0];
  const float* ln1w = (const float*)d_in[1];
  const float* ln1b = (const float*)d_in[2];
  const float* Wqkv = (const float*)d_in[3];
  const float* bqkv = (const float*)d_in[4];
  const float* qlnw = (const float*)d_in[5];
  const float* klnw = (const float*)d_in[6];
  const float* Wo   = (const float*)d_in[7];
  const float* bo   = (const float*)d_in[8];
  float* out = (float*)d_out;

  // ws layout (bytes): qkv bf16 | Ah | Al | Wth | Wtl | ctab | stab  (~209 MiB)
  const size_t qkv_b = (size_t)NT_ * 3 * HD * 2;
  const size_t a_b   = (size_t)NT_ * HD * 2;
  const size_t w_b   = (size_t)3 * HD * HD * 2;
  const size_t t_b   = (size_t)SEQ_ * 64 * 4;
  const size_t need  = qkv_b + 2 * a_b + 2 * w_b + 2 * t_b;
  if (ws_size < need) {
    ws_diag_kernel<<<1, 1, 0, stream>>>(out, (float)(ws_size >> 20));
    return;
  }
  char* w = (char*)d_ws;
  __bf16* qkvb = (__bf16*)w;              w += qkv_b;
  __bf16* Ah   = (__bf16*)w;              w += a_b;
  __bf16* Al   = (__bf16*)w;              w += a_b;
  __bf16* Wth  = (__bf16*)w;              w += w_b;
  __bf16* Wtl  = (__bf16*)w;              w += w_b;
  float*  ctab = (float*)w;               w += t_b;
  float*  stab = (float*)w;

  rope_table_kernel<<<(SEQ_ * 64 + 255) / 256, 256, 0, stream>>>(ctab, stab);
  ln1_split_kernel<false><<<NT_, 256, 0, stream>>>(x, ln1w, ln1b, Ah, Al);
  wsplit_kernel<false><<<dim3(HD / 64, 3 * HD / 64), 256, 0, stream>>>(
      Wqkv, HD, 3 * HD, Wth, Wtl);               // hi only (1-term QKV)
  gemm_bf3_kernel<1, true><<<dim3(3 * HD / 128, NT_ / 128), 256, 0, stream>>>(
      Ah, nullptr, Wth, nullptr, bqkv, qkvb, NT_, 3 * HD, HD);
  qkln_rope_kernel<<<dim3(NT_, 2), 256, 0, stream>>>(
      qkvb, qlnw, klnw, ctab, stab);
  wsplit_kernel<false><<<dim3(HD / 64, HD / 64), 256, 0, stream>>>(
      Wo, HD, HD, Wth, Wtl);                     // hi only (1-term Wo)
  attn_mfma_kernel<<<dim3(SEQ_ / 128, B_ * NH_), 256, 0, stream>>>(
      qkvb, Ah);                                 // O -> Ah (single bf16)
  gemm_bf3_kernel<1, false><<<dim3(HD / 128, NT_ / 128), 256, 0, stream>>>(
      Ah, nullptr, Wth, nullptr, bo, out, NT_, HD, HD);
}

// Round 19
// 602.312 us; speedup vs baseline: 1.2259x; 1.1769x over previous
//
#include <hip/hip_runtime.h>
#include <math.h>

#define HD   2048
#define NH_  16
#define DH_  128
#define SEQ_ 2048
#define B_   4
#define NT_  (B_*SEQ_)
#define EPS_ 1e-5f

typedef __attribute__((ext_vector_type(8))) __bf16 bf16x8;
typedef __attribute__((ext_vector_type(4))) __bf16 bf16x4;
typedef __attribute__((ext_vector_type(4))) float f32x4;

typedef const __attribute__((address_space(1))) void* gcptr_t;
typedef __attribute__((address_space(3))) void* lptr_t;

__device__ __forceinline__ void gload16(const void* g, void* l) {
  __builtin_amdgcn_global_load_lds((gcptr_t)g, (lptr_t)l, 16, 0, 0);
}

// ---------------- block-wide sum over 256 threads (4 waves) ----------------
__device__ __forceinline__ float block_sum256(float v, float* red) {
#pragma unroll
  for (int o = 32; o > 0; o >>= 1) v += __shfl_down(v, o);
  int lane = threadIdx.x & 63, wid = threadIdx.x >> 6;
  __syncthreads();
  if (lane == 0) red[wid] = v;
  __syncthreads();
  return red[0] + red[1] + red[2] + red[3];
}

// ---------------- workspace diagnostic (ws too small) ----------------------
__global__ void ws_diag_kernel(float* out, float v) { out[0] = v; }

// ---------------- RoPE cos/sin table (fp64 for accuracy) -------------------
__global__ void rope_table_kernel(float* __restrict__ ct, float* __restrict__ st) {
  int i = blockIdx.x * 256 + threadIdx.x;
  if (i >= SEQ_ * 64) return;
  int l = i >> 6, d = i & 63;
  double invf = exp2(-(double)d * (13.287712379549449 / 64.0));
  double ang = (double)l * invf;
  ct[i] = (float)cos(ang);
  st[i] = (float)sin(ang);
}

// ---------------- LN1 fused + bf16 round: x -> Ah --------------------------
template<bool LO>
__global__ __launch_bounds__(256) void ln1_split_kernel(const float* __restrict__ x,
    const float* __restrict__ w, const float* __restrict__ bias,
    __bf16* __restrict__ Ah, __bf16* __restrict__ Al) {
  __shared__ float red[4];
  int t = threadIdx.x;
  const float4* xr = (const float4*)(x + (size_t)blockIdx.x * HD);
  float4 a = xr[t], b = xr[t + 256];
  float s = a.x + a.y + a.z + a.w + b.x + b.y + b.z + b.w;
  s = block_sum256(s, red);
  float mu = s * (1.0f / HD);
  float dx[8] = {a.x - mu, a.y - mu, a.z - mu, a.w - mu,
                 b.x - mu, b.y - mu, b.z - mu, b.w - mu};
  float ss = 0.f;
#pragma unroll
  for (int i = 0; i < 8; ++i) ss += dx[i] * dx[i];
  ss = block_sum256(ss, red);
  float rs = rsqrtf(ss * (1.0f / HD) + EPS_);
  float4 w0 = ((const float4*)w)[t], w1 = ((const float4*)w)[t + 256];
  float4 b0 = ((const float4*)bias)[t], b1 = ((const float4*)bias)[t + 256];
  float y[8];
  y[0] = dx[0]*rs*w0.x + b0.x; y[1] = dx[1]*rs*w0.y + b0.y;
  y[2] = dx[2]*rs*w0.z + b0.z; y[3] = dx[3]*rs*w0.w + b0.w;
  y[4] = dx[4]*rs*w1.x + b1.x; y[5] = dx[5]*rs*w1.y + b1.y;
  y[6] = dx[6]*rs*w1.z + b1.z; y[7] = dx[7]*rs*w1.w + b1.w;
  bf16x4 h0, h1, l0, l1;
#pragma unroll
  for (int i = 0; i < 4; ++i) {
    h0[i] = (__bf16)y[i];     l0[i] = (__bf16)(y[i] - (float)h0[i]);
    h1[i] = (__bf16)y[i + 4]; l1[i] = (__bf16)(y[i + 4] - (float)h1[i]);
  }
  size_t base = (size_t)blockIdx.x * HD;
  *(bf16x4*)&Ah[base + 4 * t] = h0;
  *(bf16x4*)&Ah[base + 1024 + 4 * t] = h1;
  if (LO) {
    *(bf16x4*)&Al[base + 4 * t] = l0;
    *(bf16x4*)&Al[base + 1024 + 4 * t] = l1;
  }
}

// ---------------- W transpose + bf16 round: W[K][N] -> Wt[N][K] ------------
template<bool LO>
__global__ __launch_bounds__(256) void wsplit_kernel(const float* __restrict__ W,
    int K, int N, __bf16* __restrict__ Wh, __bf16* __restrict__ Wl) {
  __shared__ float ts[64][69];
  int k0 = blockIdx.x << 6, n0 = blockIdx.y << 6;
  int t = threadIdx.x;
#pragma unroll
  for (int i = 0; i < 16; ++i) {
    int lin = t + i * 256;
    int k = lin >> 6, n = lin & 63;
    ts[k][n] = W[(size_t)(k0 + k) * N + n0 + n];
  }
  __syncthreads();
#pragma unroll
  for (int i = 0; i < 16; ++i) {
    int lin = t + i * 256;
    int n = lin >> 6, k = lin & 63;
    float v = ts[k][n];
    __bf16 h = (__bf16)v;
    size_t o = (size_t)(n0 + n) * K + k0 + k;
    Wh[o] = h;
    if (LO) Wl[o] = (__bf16)(v - (float)h);
  }
}

// ---------------- fused Q/K layernorm (no bias) + RoPE, bf16 in place ------
__global__ __launch_bounds__(256) void qkln_rope_kernel(__bf16* __restrict__ qkv,
    const float* __restrict__ qw, const float* __restrict__ kw,
    const float* __restrict__ ct, const float* __restrict__ st) {
  __shared__ float red[4];
  int t = threadIdx.x;
  int tok = blockIdx.x;
  int part = blockIdx.y;
  int pos = tok & (SEQ_ - 1);
  __bf16* base = qkv + (size_t)tok * (3 * HD) + (size_t)part * HD;
  const float* w = part ? kw : qw;
  bf16x8 v8 = *(const bf16x8*)(base + 8 * t);
  float x[8];
#pragma unroll
  for (int i = 0; i < 8; ++i) x[i] = (float)v8[i];
  float s = 0.f;
#pragma unroll
  for (int i = 0; i < 8; ++i) s += x[i];
  s = block_sum256(s, red);
  float mu = s * (1.0f / HD);
  float ss = 0.f;
#pragma unroll
  for (int i = 0; i < 8; ++i) { x[i] -= mu; ss += x[i] * x[i]; }
  ss = block_sum256(ss, red);
  float rs = rsqrtf(ss * (1.0f / HD) + EPS_);
  float4 w0 = *(const float4*)&w[8 * t];
  float4 w1 = *(const float4*)&w[8 * t + 4];
  float y[8];
  y[0] = x[0]*rs*w0.x; y[1] = x[1]*rs*w0.y; y[2] = x[2]*rs*w0.z; y[3] = x[3]*rs*w0.w;
  y[4] = x[4]*rs*w1.x; y[5] = x[5]*rs*w1.y; y[6] = x[6]*rs*w1.z; y[7] = x[7]*rs*w1.w;
  float o[8];
#pragma unroll
  for (int i = 0; i < 8; ++i) o[i] = __shfl_xor(y[i], 8);
  int d = (8 * t) & 127;
  int dd = (d < 64) ? d : d - 64;
  float4 c0 = *(const float4*)&ct[pos * 64 + dd];
  float4 c1 = *(const float4*)&ct[pos * 64 + dd + 4];
  float4 s0 = *(const float4*)&st[pos * 64 + dd];
  float4 s1 = *(const float4*)&st[pos * 64 + dd + 4];
  float cv[8] = {c0.x, c0.y, c0.z, c0.w, c1.x, c1.y, c1.z, c1.w};
  float sv[8] = {s0.x, s0.y, s0.z, s0.w, s1.x, s1.y, s1.z, s1.w};
  bf16x8 o8;
  if (d < 64) {
#pragma unroll
    for (int i = 0; i < 8; ++i) o8[i] = (__bf16)(y[i] * cv[i] - o[i] * sv[i]);
  } else {
#pragma unroll
    for (int i = 0; i < 8; ++i) o8[i] = (__bf16)(y[i] * cv[i] + o[i] * sv[i]);
  }
  *(bf16x8*)(base + 8 * t) = o8;
}

// ---------------- split-bf16 MFMA GEMM (r5-proven structure) ---------------
template<int TERMS, bool OUTBF16>
__global__ __launch_bounds__(256, 2) void gemm_bf3_kernel(
    const __bf16* __restrict__ Ah, const __bf16* __restrict__ Al,
    const __bf16* __restrict__ Bh, const __bf16* __restrict__ Bl,
    const float* __restrict__ bias, void* __restrict__ C,
    int M, int N, int K) {
  __shared__ __bf16 lds[TERMS + 1][128][64];   // 32/48/64 KB
  constexpr int AL_OFF = 16384;
  constexpr int BH_OFF = (TERMS == 1) ? 16384 : 32768;
  constexpr int BL_OFF = 49152;
  const int t = threadIdx.x;
  const int lane = t & 63, wave = t >> 6;
  const int c = lane & 15, g = lane >> 4;
  const int wm = (wave & 1) << 6, wn = (wave >> 1) << 6;

  const int nwg = gridDim.x * gridDim.y;
  int lin = blockIdx.y * gridDim.x + blockIdx.x;
  int swz = (lin & 7) * (nwg >> 3) + (lin >> 3);
  const int col0 = (swz % gridDim.x) << 7;
  const int row0 = (swz / gridDim.x) << 7;

  const int srow = (wave << 5) + (lane >> 3);  // + i*8
  const int ch = lane & 7;
  size_t offA[4], offB[4];
#pragma unroll
  for (int i = 0; i < 4; ++i) {
    int rA = srow + i * 8;
    offA[i] = (size_t)(row0 + rA) * (K * 2) + (size_t)((ch ^ (rA & 7)) << 4);
    offB[i] = (size_t)(col0 + rA) * (K * 2) + (size_t)((ch ^ (rA & 7)) << 4);
  }
  const char* pAh = (const char*)Ah;
  const char* pAl = (const char*)Al;
  const char* pBh = (const char*)Bh;
  const char* pBl = (const char*)Bl;
  char* ldsb = (char*)&lds[0][0][0];

  float bias_[4];
#pragma unroll
  for (int nt = 0; nt < 4; ++nt) bias_[nt] = bias[col0 + wn + nt * 16 + c];

  f32x4 acc[4][4];
#pragma unroll
  for (int mt = 0; mt < 4; ++mt)
#pragma unroll
    for (int nt = 0; nt < 4; ++nt) acc[mt][nt] = f32x4{0.f, 0.f, 0.f, 0.f};

  for (int k0 = 0; k0 < K; k0 += 64) {
    const size_t k2 = (size_t)k0 * 2;
    __syncthreads();
#pragma unroll
    for (int i = 0; i < 4; ++i) {
      const int lr = (wave << 5) + (i << 3);
      gload16(pAh + offA[i] + k2, ldsb + (lr << 7));
      if (TERMS >= 2) gload16(pAl + offA[i] + k2, ldsb + AL_OFF + (lr << 7));
      gload16(pBh + offB[i] + k2, ldsb + BH_OFF + (lr << 7));
      if (TERMS == 3) gload16(pBl + offB[i] + k2, ldsb + BL_OFF + (lr << 7));
    }
    __syncthreads();
#pragma unroll
    for (int kc = 0; kc < 2; ++kc) {
      bf16x8 ah[4], al[4];
#pragma unroll
      for (int mt = 0; mt < 4; ++mt) {
        const int r = wm + mt * 16 + c;
        const int cb = (((kc << 2) | g) ^ (r & 7)) << 4;
        ah[mt] = *(const bf16x8*)(ldsb + (r << 7) + cb);
        if (TERMS >= 2) al[mt] = *(const bf16x8*)(ldsb + AL_OFF + (r << 7) + cb);
      }
#pragma unroll
      for (int nt = 0; nt < 4; ++nt) {
        const int r = wn + nt * 16 + c;
        const int cb = (((kc << 2) | g) ^ (r & 7)) << 4;
        bf16x8 bh = *(const bf16x8*)(ldsb + BH_OFF + (r << 7) + cb);
        bf16x8 bl;
        if (TERMS == 3) bl = *(const bf16x8*)(ldsb + BL_OFF + (r << 7) + cb);
#pragma unroll
        for (int mt = 0; mt < 4; ++mt) {
          acc[mt][nt] = __builtin_amdgcn_mfma_f32_16x16x32_bf16(ah[mt], bh, acc[mt][nt], 0, 0, 0);
          if (TERMS >= 2)
            acc[mt][nt] = __builtin_amdgcn_mfma_f32_16x16x32_bf16(al[mt], bh, acc[mt][nt], 0, 0, 0);
          if (TERMS == 3)
            acc[mt][nt] = __builtin_amdgcn_mfma_f32_16x16x32_bf16(ah[mt], bl, acc[mt][nt], 0, 0, 0);
        }
      }
    }
  }

#pragma unroll
  for (int mt = 0; mt < 4; ++mt) {
#pragma unroll
    for (int r = 0; r < 4; ++r) {
      const size_t row = (size_t)(row0 + wm + mt * 16 + g * 4 + r);
#pragma unroll
      for (int nt = 0; nt < 4; ++nt) {
        float v = acc[mt][nt][r] + bias_[nt];
        size_t idx = row * N + col0 + wn + nt * 16 + c;
        if (OUTBF16) ((__bf16*)C)[idx] = (__bf16)v;
        else         ((float*)C)[idx] = v;
      }
    }
  }
}

// ---------------- flash attention, bf16 MFMA, 128 q-rows per block ---------
// r19 = r16 base (322us: 48KB, 2 barriers, prefetch, __expf) with the two
// LDS-pipe shuffle reductions removed from the common path:
//  * row-max: p computed with old m; per-thread pmax (VALU fmax) detects
//    p > 2980 ~= e^8 (the old defer-max THR=8 condition exactly); only then
//    run the full shuffle-reduce/rescale/recompute slow path (first tile +
//    rare spikes). Numerics identical to r16.
//  * l-sum: ls = mfma(P_frag, ones, ls) — every D column holds the row sum;
//    D-frag layout matches l_[rt][r]. 4 extra MFMA/tile replace 32 ds-chains.
__global__ __launch_bounds__(256, 2) void attn_mfma_kernel(
    const __bf16* __restrict__ qkv, __bf16* __restrict__ Oh) {
  __shared__ __bf16 Kb[64 * 128];
  __shared__ __bf16 Vt[128 * 64];
  __shared__ __bf16 Pl[128 * 64];
  const int bh = blockIdx.y, b = bh >> 4, h = bh & 15;
  const int q0 = blockIdx.x << 7;
  const int t = threadIdx.x;
  const int lane = t & 63, wave = t >> 6, g = lane >> 4, c = lane & 15;
  const int wq = wave * 32;
  const size_t rstr = 3 * HD;
  const __bf16* Qg = qkv + (size_t)b * SEQ_ * rstr + (size_t)h * DH_;
  const __bf16* Kg = Qg + HD;
  const __bf16* Vg = Qg + 2 * HD;
  const float SC   = 0.08838834764831845f;  // 1/sqrt(128)
  const float PCAP = 2980.0f;               // e^8: defer-max trigger

  const __bf16 one_ = (__bf16)1.0f;
  const bf16x8 ones8 = {one_, one_, one_, one_, one_, one_, one_, one_};

  bf16x8 qf[2][4];
#pragma unroll
  for (int rt = 0; rt < 2; ++rt) {
    const __bf16* qr = Qg + (size_t)(q0 + wq + rt * 16 + c) * rstr;
#pragma unroll
    for (int kc = 0; kc < 4; ++kc)
      qf[rt][kc] = *(const bf16x8*)(qr + kc * 32 + g * 8);
  }

  f32x4 Oa[2][8];
#pragma unroll
  for (int rt = 0; rt < 2; ++rt)
#pragma unroll
    for (int dt = 0; dt < 8; ++dt) Oa[rt][dt] = f32x4{0.f, 0.f, 0.f, 0.f};
  f32x4 ls[2] = {f32x4{0.f, 0.f, 0.f, 0.f}, f32x4{0.f, 0.f, 0.f, 0.f}};
  float m_[2][4];
#pragma unroll
  for (int rt = 0; rt < 2; ++rt)
#pragma unroll
    for (int r = 0; r < 4; ++r) m_[rt][r] = -1e30f;

  const int krow = t >> 4;
  const int kch  = t & 15;
  const int kswc = kch ^ (krow & 7);
  const int vkey = t & 63;
  const int vd0  = (t >> 6) * 32;
  const int c7   = c & 7;

  bf16x8 kv[4], vv[4];
#define LOADT(KT)                                                            \
  {                                                                          \
    _Pragma("unroll")                                                        \
    for (int i = 0; i < 4; ++i)                                              \
      kv[i] = *(const bf16x8*)(Kg + (size_t)((KT) + krow + i * 16) * rstr + kch * 8); \
    _Pragma("unroll")                                                        \
    for (int i = 0; i < 4; ++i)                                              \
      vv[i] = *(const bf16x8*)(Vg + (size_t)((KT) + vkey) * rstr + vd0 + i * 8); \
  }
  LOADT(0);

  for (int kt = 0; kt < SEQ_; kt += 64) {
    __syncthreads();   // prev iter's LDS reads complete
#pragma unroll
    for (int i = 0; i < 4; ++i) {
      *(bf16x8*)&Kb[(krow + i * 16) * 128 + kswc * 8] = kv[i];
#pragma unroll
      for (int j = 0; j < 8; ++j)
        Vt[(vd0 + i * 8 + j) * 64 + (((vkey >> 3) ^ j) << 3) + (vkey & 7)] = vv[i][j];
    }
    __syncthreads();   // staged data visible
    if (kt + 64 < SEQ_) LOADT(kt + 64);
    // ---- S = Q K^T ----
    f32x4 Sa[2][4];
#pragma unroll
    for (int rt = 0; rt < 2; ++rt)
#pragma unroll
      for (int nt = 0; nt < 4; ++nt) Sa[rt][nt] = f32x4{0.f, 0.f, 0.f, 0.f};
#pragma unroll
    for (int nt = 0; nt < 4; ++nt) {
      bf16x8 kf[4];
#pragma unroll
      for (int kc = 0; kc < 4; ++kc)
        kf[kc] = *(bf16x8*)&Kb[(nt * 16 + c) * 128 + (((kc * 4 + g) ^ c7) << 3)];
#pragma unroll
      for (int kc = 0; kc < 4; ++kc) {
        Sa[0][nt] = __builtin_amdgcn_mfma_f32_16x16x32_bf16(qf[0][kc], kf[kc], Sa[0][nt], 0, 0, 0);
        Sa[1][nt] = __builtin_amdgcn_mfma_f32_16x16x32_bf16(qf[1][kc], kf[kc], Sa[1][nt], 0, 0, 0);
      }
    }
    // ---- P = exp(SC*(S-m_old)); per-thread overflow watch (no shuffles) ----
    float pmax = 0.f;
#pragma unroll
    for (int rt = 0; rt < 2; ++rt) {
#pragma unroll
      for (int r = 0; r < 4; ++r) {
        const float mn = m_[rt][r];
        const int prow = wq + rt * 16 + 4 * g + r;
        const int psw = prow & 7;
#pragma unroll
        for (int nt = 0; nt < 4; ++nt) {
          float p = __expf((Sa[rt][nt][r] - mn) * SC);
          pmax = fmaxf(pmax, p);
          Pl[prow * 64 + (((nt * 2 + (c >> 3)) ^ psw) << 3) + (c & 7)] = (__bf16)p;
        }
      }
    }
    if (__any(pmax > PCAP)) {
      // ---- slow path (first tile + rare spikes): true row maxes ----
      float fs_[2][4];
#pragma unroll
      for (int rt = 0; rt < 2; ++rt) {
#pragma unroll
        for (int r = 0; r < 4; ++r) {
          float mx = fmaxf(fmaxf(Sa[rt][0][r], Sa[rt][1][r]),
                           fmaxf(Sa[rt][2][r], Sa[rt][3][r]));
#pragma unroll
          for (int off = 1; off < 16; off <<= 1) mx = fmaxf(mx, __shfl_xor(mx, off));
          float mn = fmaxf(m_[rt][r], mx);
          fs_[rt][r] = __expf((m_[rt][r] - mn) * SC);
          m_[rt][r] = mn;
        }
      }
#pragma unroll
      for (int rt = 0; rt < 2; ++rt) {
        ls[rt][0] *= fs_[rt][0]; ls[rt][1] *= fs_[rt][1];
        ls[rt][2] *= fs_[rt][2]; ls[rt][3] *= fs_[rt][3];
#pragma unroll
        for (int dt = 0; dt < 8; ++dt)
#pragma unroll
          for (int r = 0; r < 4; ++r) Oa[rt][dt][r] *= fs_[rt][r];
      }
      // rewrite P with updated m
#pragma unroll
      for (int rt = 0; rt < 2; ++rt) {
#pragma unroll
        for (int r = 0; r < 4; ++r) {
          const float mn = m_[rt][r];
          const int prow = wq + rt * 16 + 4 * g + r;
          const int psw = prow & 7;
#pragma unroll
          for (int nt = 0; nt < 4; ++nt) {
            float p = __expf((Sa[rt][nt][r] - mn) * SC);
            Pl[prow * 64 + (((nt * 2 + (c >> 3)) ^ psw) << 3) + (c & 7)] = (__bf16)p;
          }
        }
      }
    }
    // ---- O += P V; l-sum via MFMA with ones (P rows own-wave) ----
#pragma unroll
    for (int k2 = 0; k2 < 2; ++k2) {
      const int pch = ((k2 * 4 + g) ^ c7) << 3;
      bf16x8 pf0 = *(bf16x8*)&Pl[(wq + c) * 64 + pch];
      bf16x8 pf1 = *(bf16x8*)&Pl[(wq + 16 + c) * 64 + pch];
      ls[0] = __builtin_amdgcn_mfma_f32_16x16x32_bf16(pf0, ones8, ls[0], 0, 0, 0);
      ls[1] = __builtin_amdgcn_mfma_f32_16x16x32_bf16(pf1, ones8, ls[1], 0, 0, 0);
#pragma unroll
      for (int dt = 0; dt < 8; ++dt) {
        bf16x8 vf = *(bf16x8*)&Vt[(dt * 16 + c) * 64 + pch];
        Oa[0][dt] = __builtin_amdgcn_mfma_f32_16x16x32_bf16(pf0, vf, Oa[0][dt], 0, 0, 0);
        Oa[1][dt] = __builtin_amdgcn_mfma_f32_16x16x32_bf16(pf1, vf, Oa[1][dt], 0, 0, 0);
      }
    }
  }
#undef LOADT
#pragma unroll
  for (int rt = 0; rt < 2; ++rt) {
#pragma unroll
    for (int r = 0; r < 4; ++r) {
      float inv = 1.0f / ls[rt][r];
      size_t obase = (size_t)(b * SEQ_ + q0 + wq + rt * 16 + 4 * g + r) * HD + h * DH_;
#pragma unroll
      for (int dt = 0; dt < 8; ++dt)
        Oh[obase + dt * 16 + c] = (__bf16)(Oa[rt][dt][r] * inv);
    }
  }
}

// ---------------------------------------------------------------------------
extern "C" void kernel_launch(void* const* d_in, const int* in_sizes, int n_in,
                              void* d_out, int out_size, void* d_ws, size_t ws_size,
                              hipStream_t stream) {
  const float* x    = (const float*)d_in[0];
  const float* ln1w = (const float*)d_in[1];
  const float* ln1b = (const float*)d_in[2];
  const float* Wqkv = (const float*)d_in[3];
  const float* bqkv = (const float*)d_in[4];
  const float* qlnw = (const float*)d_in[5];
  const float* klnw = (const float*)d_in[6];
  const float* Wo   = (const float*)d_in[7];
  const float* bo   = (const float*)d_in[8];
  float* out = (float*)d_out;

  // ws layout (bytes): qkv bf16 | Ah | Al | Wth | Wtl | ctab | stab  (~209 MiB)
  const size_t qkv_b = (size_t)NT_ * 3 * HD * 2;
  const size_t a_b   = (size_t)NT_ * HD * 2;
  const size_t w_b   = (size_t)3 * HD * HD * 2;
  const size_t t_b   = (size_t)SEQ_ * 64 * 4;
  const size_t need  = qkv_b + 2 * a_b + 2 * w_b + 2 * t_b;
  if (ws_size < need) {
    ws_diag_kernel<<<1, 1, 0, stream>>>(out, (float)(ws_size >> 20));
    return;
  }
  char* w = (char*)d_ws;
  __bf16* qkvb = (__bf16*)w;              w += qkv_b;
  __bf16* Ah   = (__bf16*)w;              w += a_b;
  __bf16* Al   = (__bf16*)w;              w += a_b;
  __bf16* Wth  = (__bf16*)w;              w += w_b;
  __bf16* Wtl  = (__bf16*)w;              w += w_b;
  float*  ctab = (float*)w;               w += t_b;
  float*  stab = (float*)w;

  rope_table_kernel<<<(SEQ_ * 64 + 255) / 256, 256, 0, stream>>>(ctab, stab);
  ln1_split_kernel<false><<<NT_, 256, 0, stream>>>(x, ln1w, ln1b, Ah, Al);
  wsplit_kernel<false><<<dim3(HD / 64, 3 * HD / 64), 256, 0, stream>>>(
      Wqkv, HD, 3 * HD, Wth, Wtl);               // hi only (1-term QKV)
  gemm_bf3_kernel<1, true><<<dim3(3 * HD / 128, NT_ / 128), 256, 0, stream>>>(
      Ah, nullptr, Wth, nullptr, bqkv, qkvb, NT_, 3 * HD, HD);
  qkln_rope_kernel<<<dim3(NT_, 2), 256, 0, stream>>>(
      qkvb, qlnw, klnw, ctab, stab);
  wsplit_kernel<false><<<dim3(HD / 64, HD / 64), 256, 0, stream>>>(
      Wo, HD, HD, Wth, Wtl);                     // hi only (1-term Wo)
  attn_mfma_kernel<<<dim3(SEQ_ / 128, B_ * NH_), 256, 0, stream>>>(
      qkvb, Ah);                                 // O -> Ah (single bf16)
  gemm_bf3_kernel<1, false><<<dim3(HD / 128, NT_ / 128), 256, 0, stream>>>(
      Ah, nullptr, Wth, nullptr, bo, out, NT_, HD, HD);
}

// Round 20
// 589.561 us; speedup vs baseline: 1.2524x; 1.0216x over previous
//
#include <hip/hip_runtime.h>
#include <math.h>

#define HD   2048
#define NH_  16
#define DH_  128
#define SEQ_ 2048
#define B_   4
#define NT_  (B_*SEQ_)
#define EPS_ 1e-5f

typedef __attribute__((ext_vector_type(8))) __bf16 bf16x8;
typedef __attribute__((ext_vector_type(4))) __bf16 bf16x4;
typedef __attribute__((ext_vector_type(4))) float f32x4;

typedef const __attribute__((address_space(1))) void* gcptr_t;
typedef __attribute__((address_space(3))) void* lptr_t;

__device__ __forceinline__ void gload16(const void* g, void* l) {
  __builtin_amdgcn_global_load_lds((gcptr_t)g, (lptr_t)l, 16, 0, 0);
}

// ---------------- block-wide sum over 256 threads (4 waves) ----------------
__device__ __forceinline__ float block_sum256(float v, float* red) {
#pragma unroll
  for (int o = 32; o > 0; o >>= 1) v += __shfl_down(v, o);
  int lane = threadIdx.x & 63, wid = threadIdx.x >> 6;
  __syncthreads();
  if (lane == 0) red[wid] = v;
  __syncthreads();
  return red[0] + red[1] + red[2] + red[3];
}

// ---------------- workspace diagnostic (ws too small) ----------------------
__global__ void ws_diag_kernel(float* out, float v) { out[0] = v; }

// ---------------- RoPE cos/sin table (fp64 for accuracy) -------------------
__global__ void rope_table_kernel(float* __restrict__ ct, float* __restrict__ st) {
  int i = blockIdx.x * 256 + threadIdx.x;
  if (i >= SEQ_ * 64) return;
  int l = i >> 6, d = i & 63;
  double invf = exp2(-(double)d * (13.287712379549449 / 64.0));
  double ang = (double)l * invf;
  ct[i] = (float)cos(ang);
  st[i] = (float)sin(ang);
}

// ---------------- LN1 fused + bf16 round: x -> Ah --------------------------
__global__ __launch_bounds__(256) void ln1_split_kernel(const float* __restrict__ x,
    const float* __restrict__ w, const float* __restrict__ bias,
    __bf16* __restrict__ Ah) {
  __shared__ float red[4];
  int t = threadIdx.x;
  const float4* xr = (const float4*)(x + (size_t)blockIdx.x * HD);
  float4 a = xr[t], b = xr[t + 256];
  float s = a.x + a.y + a.z + a.w + b.x + b.y + b.z + b.w;
  s = block_sum256(s, red);
  float mu = s * (1.0f / HD);
  float dx[8] = {a.x - mu, a.y - mu, a.z - mu, a.w - mu,
                 b.x - mu, b.y - mu, b.z - mu, b.w - mu};
  float ss = 0.f;
#pragma unroll
  for (int i = 0; i < 8; ++i) ss += dx[i] * dx[i];
  ss = block_sum256(ss, red);
  float rs = rsqrtf(ss * (1.0f / HD) + EPS_);
  float4 w0 = ((const float4*)w)[t], w1 = ((const float4*)w)[t + 256];
  float4 b0 = ((const float4*)bias)[t], b1 = ((const float4*)bias)[t + 256];
  float y[8];
  y[0] = dx[0]*rs*w0.x + b0.x; y[1] = dx[1]*rs*w0.y + b0.y;
  y[2] = dx[2]*rs*w0.z + b0.z; y[3] = dx[3]*rs*w0.w + b0.w;
  y[4] = dx[4]*rs*w1.x + b1.x; y[5] = dx[5]*rs*w1.y + b1.y;
  y[6] = dx[6]*rs*w1.z + b1.z; y[7] = dx[7]*rs*w1.w + b1.w;
  bf16x4 h0, h1;
#pragma unroll
  for (int i = 0; i < 4; ++i) {
    h0[i] = (__bf16)y[i];
    h1[i] = (__bf16)y[i + 4];
  }
  size_t base = (size_t)blockIdx.x * HD;
  *(bf16x4*)&Ah[base + 4 * t] = h0;
  *(bf16x4*)&Ah[base + 1024 + 4 * t] = h1;
}

// ---------------- W transpose + bf16 round: W[K][N] -> Wt[N][K] ------------
__global__ __launch_bounds__(256) void wsplit_kernel(const float* __restrict__ W,
    int K, int N, __bf16* __restrict__ Wh) {
  __shared__ float ts[64][69];
  int k0 = blockIdx.x << 6, n0 = blockIdx.y << 6;
  int t = threadIdx.x;
#pragma unroll
  for (int i = 0; i < 16; ++i) {
    int lin = t + i * 256;
    int k = lin >> 6, n = lin & 63;
    ts[k][n] = W[(size_t)(k0 + k) * N + n0 + n];
  }
  __syncthreads();
#pragma unroll
  for (int i = 0; i < 16; ++i) {
    int lin = t + i * 256;
    int n = lin >> 6, k = lin & 63;
    Wh[(size_t)(n0 + n) * K + k0 + k] = (__bf16)ts[k][n];
  }
}

// ---------------- fused Q/K layernorm (no bias) + RoPE, bf16 in place ------
__global__ __launch_bounds__(256) void qkln_rope_kernel(__bf16* __restrict__ qkv,
    const float* __restrict__ qw, const float* __restrict__ kw,
    const float* __restrict__ ct, const float* __restrict__ st) {
  __shared__ float red[4];
  int t = threadIdx.x;
  int tok = blockIdx.x;
  int part = blockIdx.y;
  int pos = tok & (SEQ_ - 1);
  __bf16* base = qkv + (size_t)tok * (3 * HD) + (size_t)part * HD;
  const float* w = part ? kw : qw;
  bf16x8 v8 = *(const bf16x8*)(base + 8 * t);
  float x[8];
#pragma unroll
  for (int i = 0; i < 8; ++i) x[i] = (float)v8[i];
  float s = 0.f;
#pragma unroll
  for (int i = 0; i < 8; ++i) s += x[i];
  s = block_sum256(s, red);
  float mu = s * (1.0f / HD);
  float ss = 0.f;
#pragma unroll
  for (int i = 0; i < 8; ++i) { x[i] -= mu; ss += x[i] * x[i]; }
  ss = block_sum256(ss, red);
  float rs = rsqrtf(ss * (1.0f / HD) + EPS_);
  float4 w0 = *(const float4*)&w[8 * t];
  float4 w1 = *(const float4*)&w[8 * t + 4];
  float y[8];
  y[0] = x[0]*rs*w0.x; y[1] = x[1]*rs*w0.y; y[2] = x[2]*rs*w0.z; y[3] = x[3]*rs*w0.w;
  y[4] = x[4]*rs*w1.x; y[5] = x[5]*rs*w1.y; y[6] = x[6]*rs*w1.z; y[7] = x[7]*rs*w1.w;
  float o[8];
#pragma unroll
  for (int i = 0; i < 8; ++i) o[i] = __shfl_xor(y[i], 8);
  int d = (8 * t) & 127;
  int dd = (d < 64) ? d : d - 64;
  float4 c0 = *(const float4*)&ct[pos * 64 + dd];
  float4 c1 = *(const float4*)&ct[pos * 64 + dd + 4];
  float4 s0 = *(const float4*)&st[pos * 64 + dd];
  float4 s1 = *(const float4*)&st[pos * 64 + dd + 4];
  float cv[8] = {c0.x, c0.y, c0.z, c0.w, c1.x, c1.y, c1.z, c1.w};
  float sv[8] = {s0.x, s0.y, s0.z, s0.w, s1.x, s1.y, s1.z, s1.w};
  bf16x8 o8;
  if (d < 64) {
#pragma unroll
    for (int i = 0; i < 8; ++i) o8[i] = (__bf16)(y[i] * cv[i] - o[i] * sv[i]);
  } else {
#pragma unroll
    for (int i = 0; i < 8; ++i) o8[i] = (__bf16)(y[i] * cv[i] + o[i] * sv[i]);
  }
  *(bf16x8*)(base + 8 * t) = o8;
}

// ---------------- pure-bf16 MFMA GEMM, BK=128 (r5 sync structure) ----------
// C = A * Bt^T + bias. A: [M][K] bf16; Bt: [N][K] bf16.
// BM=BN=128, BK=128, 256 thr (4 waves 2x2), wave tile 64x64, 16x16x32 MFMA.
// LDS [2][128][128] = 64KB (A, B tiles). Same 2-barrier loop as r5-r19
// (parameter change only; sync structure inherited/proven). Halves the
// barrier-drain count per K vs BK=64: 16 steps x 64 MFMA/wave.
// Swizzle (involution, proven family): 16B-chunk position p of row r holds
// global chunk p^(r&7). gload dest wave-uniform linear (4 rows x 256B per
// issue; HW adds lane*16); source pre-swizzled: lane (l4=lane>>4, ch=lane&15)
// loads chunk ch^(srow&7), srow&7 = l4 (even issues) or l4+4 (odd).
// Read: chunk (kc*4+g)^(r&7); 2 lanes/bank-slot = conflict-free.
template<bool OUTBF16>
__global__ __launch_bounds__(256, 2) void gemm_bf1_kernel(
    const __bf16* __restrict__ A, const __bf16* __restrict__ Bt,
    const float* __restrict__ bias, void* __restrict__ C,
    int M, int N, int K) {
  __shared__ __bf16 lds[2][128][128];   // 64KB
  const int t = threadIdx.x;
  const int lane = t & 63, wave = t >> 6;
  const int c = lane & 15, g = lane >> 4;
  const int wm = (wave & 1) << 6, wn = (wave >> 1) << 6;

  // XCD-aware block swizzle (nwg % 8 == 0 for all our grids)
  const int nwg = gridDim.x * gridDim.y;
  int lin = blockIdx.y * gridDim.x + blockIdx.x;
  int swz = (lin & 7) * (nwg >> 3) + (lin >> 3);
  const int col0 = (swz % gridDim.x) << 7;
  const int row0 = (swz / gridDim.x) << 7;

  // staging bases: wave stages rows [w*32, w*32+32), 8 issues x 4 rows/array
  const int l4 = lane >> 4;          // row within 4-row group
  const int ch = lane & 15;          // chunk 0..15
  const size_t K2 = (size_t)K * 2;
  const size_t swzE = (size_t)((ch ^ l4) << 4);
  const size_t swzO = (size_t)((ch ^ (l4 + 4)) << 4);
  const char* pAe = (const char*)A  + (size_t)(row0 + (wave << 5)     + l4) * K2 + swzE;
  const char* pAo = (const char*)A  + (size_t)(row0 + (wave << 5) + 4 + l4) * K2 + swzO;
  const char* pBe = (const char*)Bt + (size_t)(col0 + (wave << 5)     + l4) * K2 + swzE;
  const char* pBo = (const char*)Bt + (size_t)(col0 + (wave << 5) + 4 + l4) * K2 + swzO;
  char* ldsb = (char*)&lds[0][0][0];

#define STAGE1(kbyte)                                                        \
  {                                                                          \
    _Pragma("unroll")                                                        \
    for (int j = 0; j < 4; ++j) {                                            \
      const size_t rj = (size_t)j * 8 * K2;                                  \
      char* dA = ldsb + (wave << 13) + (j << 11);                            \
      gload16(pAe + rj + (kbyte), dA);                                       \
      gload16(pAo + rj + (kbyte), dA + 1024);                                \
      gload16(pBe + rj + (kbyte), dA + 32768);                               \
      gload16(pBo + rj + (kbyte), dA + 33792);                               \
    }                                                                        \
  }

  float bias_[4];
#pragma unroll
  for (int nt = 0; nt < 4; ++nt) bias_[nt] = bias[col0 + wn + nt * 16 + c];

  f32x4 acc[4][4];
#pragma unroll
  for (int mt = 0; mt < 4; ++mt)
#pragma unroll
    for (int nt = 0; nt < 4; ++nt) acc[mt][nt] = f32x4{0.f, 0.f, 0.f, 0.f};

  for (int k0 = 0; k0 < K; k0 += 128) {
    __syncthreads();            // previous step's frag reads complete
    STAGE1((size_t)k0 * 2);
    __syncthreads();            // drain: staged data visible
#pragma unroll
    for (int kc = 0; kc < 4; ++kc) {
      bf16x8 ah[4];
#pragma unroll
      for (int mt = 0; mt < 4; ++mt) {
        const int r = wm + mt * 16 + c;
        const int cb = (((kc << 2) | g) ^ (r & 7)) << 4;
        ah[mt] = *(const bf16x8*)(ldsb + (r << 8) + cb);
      }
#pragma unroll
      for (int nt = 0; nt < 4; ++nt) {
        const int r = wn + nt * 16 + c;
        const int cb = (((kc << 2) | g) ^ (r & 7)) << 4;
        bf16x8 bh = *(const bf16x8*)(ldsb + 32768 + (r << 8) + cb);
#pragma unroll
        for (int mt = 0; mt < 4; ++mt)
          acc[mt][nt] = __builtin_amdgcn_mfma_f32_16x16x32_bf16(ah[mt], bh, acc[mt][nt], 0, 0, 0);
      }
    }
  }
#undef STAGE1

  // epilogue: D-frag row = g*4+r, col = c
#pragma unroll
  for (int mt = 0; mt < 4; ++mt) {
#pragma unroll
    for (int r = 0; r < 4; ++r) {
      const size_t row = (size_t)(row0 + wm + mt * 16 + g * 4 + r);
#pragma unroll
      for (int nt = 0; nt < 4; ++nt) {
        float v = acc[mt][nt][r] + bias_[nt];
        size_t idx = row * N + col0 + wn + nt * 16 + c;
        if (OUTBF16) ((__bf16*)C)[idx] = (__bf16)v;
        else         ((float*)C)[idx] = v;
      }
    }
  }
}

// ---------------- flash attention, bf16 MFMA, 128 q-rows per block ---------
// r19-proven: shuffle-free common path (overflow-triggered slow path),
// l-sum via MFMA(ones), swizzled 0-conflict LDS, prefetch, 2 barriers/tile.
__global__ __launch_bounds__(256, 2) void attn_mfma_kernel(
    const __bf16* __restrict__ qkv, __bf16* __restrict__ Oh) {
  __shared__ __bf16 Kb[64 * 128];
  __shared__ __bf16 Vt[128 * 64];
  __shared__ __bf16 Pl[128 * 64];
  const int bh = blockIdx.y, b = bh >> 4, h = bh & 15;
  const int q0 = blockIdx.x << 7;
  const int t = threadIdx.x;
  const int lane = t & 63, wave = t >> 6, g = lane >> 4, c = lane & 15;
  const int wq = wave * 32;
  const size_t rstr = 3 * HD;
  const __bf16* Qg = qkv + (size_t)b * SEQ_ * rstr + (size_t)h * DH_;
  const __bf16* Kg = Qg + HD;
  const __bf16* Vg = Qg + 2 * HD;
  const float SC   = 0.08838834764831845f;  // 1/sqrt(128)
  const float PCAP = 2980.0f;               // e^8: defer-max trigger

  const __bf16 one_ = (__bf16)1.0f;
  const bf16x8 ones8 = {one_, one_, one_, one_, one_, one_, one_, one_};

  bf16x8 qf[2][4];
#pragma unroll
  for (int rt = 0; rt < 2; ++rt) {
    const __bf16* qr = Qg + (size_t)(q0 + wq + rt * 16 + c) * rstr;
#pragma unroll
    for (int kc = 0; kc < 4; ++kc)
      qf[rt][kc] = *(const bf16x8*)(qr + kc * 32 + g * 8);
  }

  f32x4 Oa[2][8];
#pragma unroll
  for (int rt = 0; rt < 2; ++rt)
#pragma unroll
    for (int dt = 0; dt < 8; ++dt) Oa[rt][dt] = f32x4{0.f, 0.f, 0.f, 0.f};
  f32x4 ls[2] = {f32x4{0.f, 0.f, 0.f, 0.f}, f32x4{0.f, 0.f, 0.f, 0.f}};
  float m_[2][4];
#pragma unroll
  for (int rt = 0; rt < 2; ++rt)
#pragma unroll
    for (int r = 0; r < 4; ++r) m_[rt][r] = -1e30f;

  const int krow = t >> 4;
  const int kch  = t & 15;
  const int kswc = kch ^ (krow & 7);
  const int vkey = t & 63;
  const int vd0  = (t >> 6) * 32;
  const int c7   = c & 7;

  bf16x8 kv[4], vv[4];
#define LOADT(KT)                                                            \
  {                                                                          \
    _Pragma("unroll")                                                        \
    for (int i = 0; i < 4; ++i)                                              \
      kv[i] = *(const bf16x8*)(Kg + (size_t)((KT) + krow + i * 16) * rstr + kch * 8); \
    _Pragma("unroll")                                                        \
    for (int i = 0; i < 4; ++i)                                              \
      vv[i] = *(const bf16x8*)(Vg + (size_t)((KT) + vkey) * rstr + vd0 + i * 8); \
  }
  LOADT(0);

  for (int kt = 0; kt < SEQ_; kt += 64) {
    __syncthreads();   // prev iter's LDS reads complete
#pragma unroll
    for (int i = 0; i < 4; ++i) {
      *(bf16x8*)&Kb[(krow + i * 16) * 128 + kswc * 8] = kv[i];
#pragma unroll
      for (int j = 0; j < 8; ++j)
        Vt[(vd0 + i * 8 + j) * 64 + (((vkey >> 3) ^ j) << 3) + (vkey & 7)] = vv[i][j];
    }
    __syncthreads();   // staged data visible
    if (kt + 64 < SEQ_) LOADT(kt + 64);
    // ---- S = Q K^T ----
    f32x4 Sa[2][4];
#pragma unroll
    for (int rt = 0; rt < 2; ++rt)
#pragma unroll
      for (int nt = 0; nt < 4; ++nt) Sa[rt][nt] = f32x4{0.f, 0.f, 0.f, 0.f};
#pragma unroll
    for (int nt = 0; nt < 4; ++nt) {
      bf16x8 kf[4];
#pragma unroll
      for (int kc = 0; kc < 4; ++kc)
        kf[kc] = *(bf16x8*)&Kb[(nt * 16 + c) * 128 + (((kc * 4 + g) ^ c7) << 3)];
#pragma unroll
      for (int kc = 0; kc < 4; ++kc) {
        Sa[0][nt] = __builtin_amdgcn_mfma_f32_16x16x32_bf16(qf[0][kc], kf[kc], Sa[0][nt], 0, 0, 0);
        Sa[1][nt] = __builtin_amdgcn_mfma_f32_16x16x32_bf16(qf[1][kc], kf[kc], Sa[1][nt], 0, 0, 0);
      }
    }
    // ---- P = exp(SC*(S-m_old)); per-thread overflow watch (no shuffles) ----
    float pmax = 0.f;
#pragma unroll
    for (int rt = 0; rt < 2; ++rt) {
#pragma unroll
      for (int r = 0; r < 4; ++r) {
        const float mn = m_[rt][r];
        const int prow = wq + rt * 16 + 4 * g + r;
        const int psw = prow & 7;
#pragma unroll
        for (int nt = 0; nt < 4; ++nt) {
          float p = __expf((Sa[rt][nt][r] - mn) * SC);
          pmax = fmaxf(pmax, p);
          Pl[prow * 64 + (((nt * 2 + (c >> 3)) ^ psw) << 3) + (c & 7)] = (__bf16)p;
        }
      }
    }
    if (__any(pmax > PCAP)) {
      // ---- slow path (first tile + rare spikes): true row maxes ----
      float fs_[2][4];
#pragma unroll
      for (int rt = 0; rt < 2; ++rt) {
#pragma unroll
        for (int r = 0; r < 4; ++r) {
          float mx = fmaxf(fmaxf(Sa[rt][0][r], Sa[rt][1][r]),
                           fmaxf(Sa[rt][2][r], Sa[rt][3][r]));
#pragma unroll
          for (int off = 1; off < 16; off <<= 1) mx = fmaxf(mx, __shfl_xor(mx, off));
          float mn = fmaxf(m_[rt][r], mx);
          fs_[rt][r] = __expf((m_[rt][r] - mn) * SC);
          m_[rt][r] = mn;
        }
      }
#pragma unroll
      for (int rt = 0; rt < 2; ++rt) {
        ls[rt][0] *= fs_[rt][0]; ls[rt][1] *= fs_[rt][1];
        ls[rt][2] *= fs_[rt][2]; ls[rt][3] *= fs_[rt][3];
#pragma unroll
        for (int dt = 0; dt < 8; ++dt)
#pragma unroll
          for (int r = 0; r < 4; ++r) Oa[rt][dt][r] *= fs_[rt][r];
      }
      // rewrite P with updated m
#pragma unroll
      for (int rt = 0; rt < 2; ++rt) {
#pragma unroll
        for (int r = 0; r < 4; ++r) {
          const float mn = m_[rt][r];
          const int prow = wq + rt * 16 + 4 * g + r;
          const int psw = prow & 7;
#pragma unroll
          for (int nt = 0; nt < 4; ++nt) {
            float p = __expf((Sa[rt][nt][r] - mn) * SC);
            Pl[prow * 64 + (((nt * 2 + (c >> 3)) ^ psw) << 3) + (c & 7)] = (__bf16)p;
          }
        }
      }
    }
    // ---- O += P V; l-sum via MFMA with ones (P rows own-wave) ----
#pragma unroll
    for (int k2 = 0; k2 < 2; ++k2) {
      const int pch = ((k2 * 4 + g) ^ c7) << 3;
      bf16x8 pf0 = *(bf16x8*)&Pl[(wq + c) * 64 + pch];
      bf16x8 pf1 = *(bf16x8*)&Pl[(wq + 16 + c) * 64 + pch];
      ls[0] = __builtin_amdgcn_mfma_f32_16x16x32_bf16(pf0, ones8, ls[0], 0, 0, 0);
      ls[1] = __builtin_amdgcn_mfma_f32_16x16x32_bf16(pf1, ones8, ls[1], 0, 0, 0);
#pragma unroll
      for (int dt = 0; dt < 8; ++dt) {
        bf16x8 vf = *(bf16x8*)&Vt[(dt * 16 + c) * 64 + pch];
        Oa[0][dt] = __builtin_amdgcn_mfma_f32_16x16x32_bf16(pf0, vf, Oa[0][dt], 0, 0, 0);
        Oa[1][dt] = __builtin_amdgcn_mfma_f32_16x16x32_bf16(pf1, vf, Oa[1][dt], 0, 0, 0);
      }
    }
  }
#undef LOADT
#pragma unroll
  for (int rt = 0; rt < 2; ++rt) {
#pragma unroll
    for (int r = 0; r < 4; ++r) {
      float inv = 1.0f / ls[rt][r];
      size_t obase = (size_t)(b * SEQ_ + q0 + wq + rt * 16 + 4 * g + r) * HD + h * DH_;
#pragma unroll
      for (int dt = 0; dt < 8; ++dt)
        Oh[obase + dt * 16 + c] = (__bf16)(Oa[rt][dt][r] * inv);
    }
  }
}

// ---------------------------------------------------------------------------
extern "C" void kernel_launch(void* const* d_in, const int* in_sizes, int n_in,
                              void* d_out, int out_size, void* d_ws, size_t ws_size,
                              hipStream_t stream) {
  const float* x    = (const float*)d_in[0];
  const float* ln1w = (const float*)d_in[1];
  const float* ln1b = (const float*)d_in[2];
  const float* Wqkv = (const float*)d_in[3];
  const float* bqkv = (const float*)d_in[4];
  const float* qlnw = (const float*)d_in[5];
  const float* klnw = (const float*)d_in[6];
  const float* Wo   = (const float*)d_in[7];
  const float* bo   = (const float*)d_in[8];
  float* out = (float*)d_out;

  // ws layout (bytes): qkv bf16 | Ah | Al | Wth | Wtl | ctab | stab  (~209 MiB)
  const size_t qkv_b = (size_t)NT_ * 3 * HD * 2;
  const size_t a_b   = (size_t)NT_ * HD * 2;
  const size_t w_b   = (size_t)3 * HD * HD * 2;
  const size_t t_b   = (size_t)SEQ_ * 64 * 4;
  const size_t need  = qkv_b + 2 * a_b + 2 * w_b + 2 * t_b;
  if (ws_size < need) {
    ws_diag_kernel<<<1, 1, 0, stream>>>(out, (float)(ws_size >> 20));
    return;
  }
  char* w = (char*)d_ws;
  __bf16* qkvb = (__bf16*)w;              w += qkv_b;
  __bf16* Ah   = (__bf16*)w;              w += a_b;
  __bf16* Al   = (__bf16*)w;              w += a_b;
  __bf16* Wth  = (__bf16*)w;              w += w_b;
  __bf16* Wtl  = (__bf16*)w;              w += w_b;
  float*  ctab = (float*)w;               w += t_b;
  float*  stab = (float*)w;
  (void)Al; (void)Wtl;

  rope_table_kernel<<<(SEQ_ * 64 + 255) / 256, 256, 0, stream>>>(ctab, stab);
  ln1_split_kernel<<<NT_, 256, 0, stream>>>(x, ln1w, ln1b, Ah);
  wsplit_kernel<<<dim3(HD / 64, 3 * HD / 64), 256, 0, stream>>>(
      Wqkv, HD, 3 * HD, Wth);
  gemm_bf1_kernel<true><<<dim3(3 * HD / 128, NT_ / 128), 256, 0, stream>>>(
      Ah, Wth, bqkv, qkvb, NT_, 3 * HD, HD);
  qkln_rope_kernel<<<dim3(NT_, 2), 256, 0, stream>>>(
      qkvb, qlnw, klnw, ctab, stab);
  wsplit_kernel<<<dim3(HD / 64, HD / 64), 256, 0, stream>>>(
      Wo, HD, HD, Wth);                          // after QKV GEMM (reuse)
  attn_mfma_kernel<<<dim3(SEQ_ / 128, B_ * NH_), 256, 0, stream>>>(
      qkvb, Ah);                                 // O -> Ah (single bf16)
  gemm_bf1_kernel<false><<<dim3(HD / 128, NT_ / 128), 256, 0, stream>>>(
      Ah, Wth, bo, out, NT_, HD, HD);
}